// Round 14
// baseline (903.598 us; speedup 1.0000x reference)
//
#include <hip/hip_runtime.h>
#include <hip/hip_fp16.h>
#include <math.h>

// ---------------- problem constants ----------------
namespace {
constexpr int kB   = 4;
constexpr int kNG  = 100;
constexpr int kH1  = 112;            // feat H/W
constexpr int kH2  = 224;            // upscaled H/W
constexpr int kQ   = kH2 * kH2;      // 50176 queries per batch image
constexpr int kP1  = kH1 * kH1;      // 12544 pixels per image (feat res)

// ---- path B (per-image loop) workspace layout, ~79 MB ----
constexpr size_t B_FBH  = 0;
constexpr size_t B_FBL  = 6422528;
constexpr size_t B_GFH  = 0;
constexpr size_t B_GFL  = 6422528;
constexpr size_t B_H    = 12845056;
constexpr size_t B_CF   = 25690112;
constexpr size_t B_WBASE= B_CF + 51380224;

// ---- path A (batched) workspace layout, ~259 MB ----
constexpr size_t A_FBH  = 0;
constexpr size_t A_FBL  = 6422528;
constexpr size_t A_H    = 12845056;
constexpr size_t A_GFH  = 0;
constexpr size_t A_GFL  = 25690112;
constexpr size_t A_CF   = 51380224;
constexpr size_t A_WBASE= A_CF + 205520896;
constexpr size_t A_TOTAL= A_WBASE + 1893376;

// weight region offsets (relative to WBASE)
constexpr size_t W_WPH  = 0;
constexpr size_t W_WPL  = 589824;
constexpr size_t W_W1H  = 1179648;
constexpr size_t W_W1L  = 1253376;
constexpr size_t W_WMLP = 1327104;
constexpr size_t W_WSUM = 1851392;
constexpr size_t W_WK   = 1852416;
}  // namespace

using s8v = __attribute__((ext_vector_type(8))) short;   // 8 bf16 (4 VGPRs)
using f4v = __attribute__((ext_vector_type(4))) float;   // MFMA acc
using u4v = __attribute__((ext_vector_type(4))) unsigned int;

__device__ __forceinline__ unsigned short f2bf(float f) {
  unsigned int u = __float_as_uint(f);
  unsigned int r = u + 0x7fffu + ((u >> 16) & 1u);
  return (unsigned short)(r >> 16);
}
__device__ __forceinline__ float bf2f(unsigned short h) {
  return __uint_as_float((unsigned int)h << 16);
}
__device__ __forceinline__ unsigned short f2h(float f) {
  return __builtin_bit_cast(unsigned short, __float2half(f));
}
__device__ __forceinline__ float h2f(unsigned short u) {
  return __half2float(__builtin_bit_cast(__half, u));
}

// ---------------- tiny helpers ----------------
__global__ void k_init(float* wsums) {
  int t = threadIdx.x;
  if (t < 196) wsums[t] = 0.0f;
}

__global__ __launch_bounds__(256) void k_prepfeat(const float* __restrict__ feat,
                                                  unsigned short* __restrict__ fbh,
                                                  unsigned short* __restrict__ fbl) {
  __shared__ float ls[64 * 65];
  const int t = threadIdx.x;
  const int b = blockIdx.x / 196;
  const int seg = blockIdx.x % 196;
  const int pixbase = seg * 64;
  for (int idx = t; idx < 4096; idx += 256) {
    int ci = idx >> 6, px = idx & 63;
    ls[px * 65 + ci] = feat[((size_t)(b * 64 + ci)) * kP1 + pixbase + px];
  }
  __syncthreads();
  for (int idx = t; idx < 4096; idx += 256) {
    int px = idx >> 6, ci = idx & 63;
    float v = ls[px * 65 + ci];
    unsigned short hi = f2bf(v);
    unsigned short lo = f2bf(v - bf2f(hi));
    size_t o = ((size_t)(b * kP1 + pixbase + px)) * 64 + ci;
    fbh[o] = hi;
    fbl[o] = lo;
  }
}

__global__ void k_prepw(const float* __restrict__ cw, const float* __restrict__ fw,
                        unsigned short* __restrict__ wph, unsigned short* __restrict__ wpl) {
  int e = blockIdx.x * 256 + threadIdx.x;   // 512*576
  int co = e / 576, k = e % 576;
  int ci = k & 63, kk = k >> 6;
  float v = (co < 256) ? cw[co * 576 + ci * 9 + kk] : fw[(co - 256) * 576 + ci * 9 + kk];
  unsigned short hi = f2bf(v);
  unsigned short lo = f2bf(v - bf2f(hi));
  int n16 = co >> 4, nl = co & 15;
  int kstep = k >> 5, kr = k & 31;
  int dst = ((n16 * 18 + kstep) * 64 + (kr >> 3) * 16 + nl) * 8 + (kr & 7);
  wph[dst] = hi;
  wpl[dst] = lo;
}

__global__ void k_prepw1(const float* __restrict__ w1src,
                         unsigned short* __restrict__ wph, unsigned short* __restrict__ wpl) {
  int e = blockIdx.x * 256 + threadIdx.x;   // 64*576
  int co = e / 576, k = e % 576;
  int ci = k & 63, kk = k >> 6;
  float v = w1src[co * 576 + ci * 9 + kk];
  unsigned short hi = f2bf(v);
  unsigned short lo = f2bf(v - bf2f(hi));
  int n16 = co >> 4, nl = co & 15;
  int kstep = k >> 5, kr = k & 31;
  int dst = ((n16 * 18 + kstep) * 64 + (kr >> 3) * 16 + nl) * 8 + (kr & 7);
  wph[dst] = hi;
  wpl[dst] = lo;
}

__global__ void k_prepmlp(const float* __restrict__ w1, const float* __restrict__ w2,
                          unsigned short* __restrict__ wp) {
  int e = blockIdx.x * 256 + threadIdx.x;   // 131072
  int mat = e >> 16, idx = e & 65535;
  int j = idx >> 8, k = idx & 255;
  float v = (mat ? w2 : w1)[j * 256 + k];
  unsigned short hi = f2bf(v);
  unsigned short lo = f2bf(v - bf2f(hi));
  int n16 = j >> 4, nl = j & 15;
  int kstep = k >> 5, kr = k & 31;
  int dst = ((n16 * 8 + kstep) * 64 + (kr >> 3) * 16 + nl) * 8 + (kr & 7);
  wp[mat * 131072 + dst] = hi;
  wp[mat * 131072 + 65536 + dst] = lo;
}

// ---------------- conv1 as bf16x3 MFMA implicit GEMM ----------------
__global__ __launch_bounds__(256) void k_conv1_mfma(
    const unsigned short* __restrict__ fbh, const unsigned short* __restrict__ fbl,
    const unsigned short* __restrict__ wph, const unsigned short* __restrict__ wpl,
    const float* __restrict__ bias, float* __restrict__ outp) {
  __shared__ __attribute__((aligned(16))) char Asb[2 * 180 * 144];
  const int t = threadIdx.x;
  const int blk = blockIdx.x;          // 392
  const int b = blk / 98;
  const int mt = blk % 98;
  const int ty = mt / 14, tx = mt % 14;
  const int py0 = ty * 16, px0 = tx * 8;

  for (int idx = t; idx < 2880; idx += 256) {
    int plane = idx >= 1440;
    int r2 = plane ? idx - 1440 : idx;
    int p = r2 >> 3, c8 = r2 & 7;
    int pr = p / 10, pc = p % 10;
    int gy = py0 - 1 + pr, gx = px0 - 1 + pc;
    uint4 u = make_uint4(0u, 0u, 0u, 0u);
    if (gy >= 0 && gy < kH1 && gx >= 0 && gx < kH1) {
      const unsigned short* src = (plane ? fbl : fbh) +
          ((size_t)(b * kP1 + gy * kH1 + gx)) * 64 + c8 * 8;
      u = *(const uint4*)src;
    }
    *(uint4*)(Asb + plane * 25920 + p * 144 + c8 * 16) = u;
  }
  __syncthreads();

  const int w = t >> 6, lane = t & 63;
  const int quad = lane >> 4, ml = lane & 15;

  f4v acc[8];
#pragma unroll
  for (int i = 0; i < 8; ++i) acc[i] = (f4v){0.0f, 0.0f, 0.0f, 0.0f};

  const unsigned int bvoff = (unsigned int)lane * 16u;
#pragma unroll
  for (int kk = 0; kk < 9; ++kk) {
    const int ky = kk / 3, kx = kk % 3;
#pragma unroll
    for (int cs = 0; cs < 2; ++cs) {
      const int kstep = kk * 2 + cs;
      unsigned int off = ((unsigned int)(w * 18 + kstep)) * 1024u + bvoff;
      s8v Bh = *(const s8v*)((const char*)wph + off);
      s8v Bl = *(const s8v*)((const char*)wpl + off);
#pragma unroll
      for (int i = 0; i < 8; ++i) {
        const int aoff = ((2 * i + (ml >> 3) + ky) * 10 + (ml & 7) + kx) * 144 + cs * 64 + quad * 16;
        s8v Ah = *(const s8v*)(Asb + aoff);
        s8v Al = *(const s8v*)(Asb + 25920 + aoff);
        acc[i] = __builtin_amdgcn_mfma_f32_16x16x32_bf16(Ah, Bh, acc[i], 0, 0, 0);
        acc[i] = __builtin_amdgcn_mfma_f32_16x16x32_bf16(Al, Bh, acc[i], 0, 0, 0);
        acc[i] = __builtin_amdgcn_mfma_f32_16x16x32_bf16(Ah, Bl, acc[i], 0, 0, 0);
      }
    }
  }

  const float bv = bias[w * 16 + ml];
#pragma unroll
  for (int i = 0; i < 8; ++i)
#pragma unroll
    for (int reg = 0; reg < 4; ++reg) {
      int m = i * 16 + quad * 4 + reg;
      int Y = py0 + (m >> 3), X = px0 + (m & 7);
      outp[((size_t)(b * kP1 + Y * kH1 + X)) * 64 + w * 16 + ml] =
          fmaxf(acc[i][reg] + bv, 0.0f);
    }
}

// ---------------- 1x1 conv + softmax + weighted sums ----------------
__global__ __launch_bounds__(256) void k_wavg(
    const float* __restrict__ h, const float* __restrict__ w2, const float* __restrict__ b2,
    const float* __restrict__ sx, const float* __restrict__ sy,
    const float* __restrict__ op, const float* __restrict__ rho,
    float* __restrict__ wsums) {
  __shared__ float w2s[kNG * 64];
  __shared__ float prm[4 * kNG];
  __shared__ float b2s[kNG];
  __shared__ float pl[196];
  const int t = threadIdx.x;
  for (int i = t; i < kNG * 64; i += 256) w2s[i] = w2[i];
  if (t < kNG) {
    prm[t] = sx[t];
    prm[kNG + t] = sy[t];
    prm[2 * kNG + t] = op[t];
    prm[3 * kNG + t] = rho[t];
    b2s[t] = b2[t];
  }
  if (t < 196) pl[t] = 0.0f;
  __syncthreads();
  const int id = blockIdx.x * 256 + t;
  float hreg[64];
  const float4* hp = (const float4*)(h + (size_t)id * 64);
#pragma unroll
  for (int i = 0; i < 16; ++i) {
    float4 v = hp[i];
    hreg[4 * i] = v.x; hreg[4 * i + 1] = v.y;
    hreg[4 * i + 2] = v.z; hreg[4 * i + 3] = v.w;
  }
  float S = 0, Sx = 0, Sy = 0, So = 0, Sr = 0;
  for (int g = 0; g < kNG; ++g) {
    float d = b2s[g];
    const float4* wp = (const float4*)(w2s + g * 64);
#pragma unroll
    for (int i = 0; i < 16; ++i) {
      float4 w = wp[i];
      d += hreg[4 * i] * w.x + hreg[4 * i + 1] * w.y +
           hreg[4 * i + 2] * w.z + hreg[4 * i + 3] * w.w;
    }
    float e = expf(d);
    S += e;
    Sx += e * prm[g];
    Sy += e * prm[kNG + g];
    So += e * prm[2 * kNG + g];
    Sr += e * prm[3 * kNG + g];
  }
  const int rem = id % (kH1 * kH1);
  const int p = ((rem / kH1) % 7) * 7 + ((rem % kH1) % 7);
  const float inv = 1.0f / S;
  atomicAdd(&pl[p], Sx * inv);
  atomicAdd(&pl[49 + p], Sy * inv);
  atomicAdd(&pl[98 + p], So * inv);
  atomicAdd(&pl[147 + p], Sr * inv);
  __syncthreads();
  if (t < 196) atomicAdd(&wsums[t], pl[t]);
}

// ---------------- build wk[p][h][w] ----------------
__global__ __launch_bounds__(256) void k_finalize(const float* __restrict__ wsums,
                                                  float* __restrict__ wk) {
  __shared__ float kern_s[49 * 25];
  __shared__ float wavg_s[196];
  const int t = threadIdx.x;
  if (t < 196) wavg_s[t] = wsums[t] * (1.0f / 1024.0f);
  __syncthreads();
  if (t < 49) {
    float wsx = wavg_s[t], wsy = wavg_s[49 + t], wr = wavg_s[147 + t];
    float c00 = wsx * wsx + 1e-5f;
    float c11 = wsy * wsy + 1e-5f;
    float c01 = wr * wsx * wsy;
    float det = c00 * c11 - c01 * c01;
    float i00 = c11 / det, i11 = c00 / det, i01 = -c01 / det;
    float nrm = 1.0f / (2.0f * 3.14159265358979323846f * sqrtf(det));
    float vals[25];
    float mx = -1e30f;
#pragma unroll
    for (int i = 0; i < 5; ++i) {
#pragma unroll
      for (int j = 0; j < 5; ++j) {
        float yv = -5.0f + 2.5f * (float)i;
        float xv = -5.0f + 2.5f * (float)j;
        float z = -0.5f * (i00 * xv * xv + 2.0f * i01 * xv * yv + i11 * yv * yv);
        float v = expf(z) * nrm;
        vals[i * 5 + j] = v;
        mx = fmaxf(mx, v);
      }
    }
#pragma unroll
    for (int k = 0; k < 25; ++k) kern_s[t * 25 + k] = vals[k] / mx;
  }
  __syncthreads();
  for (int idx = t; idx < 49 * 196; idx += 256) {
    const int p = idx / 196;
    const int hw = idx % 196;
    const int hh = hw / 14, ww = hw % 14;
    float txv = (0.5f - (float)(p / 7) / 7.0f) * 2.0f;
    float tyv = (0.5f - (float)(p % 7) / 7.0f) * 2.0f;
    float gxv = (-1.0f + (float)ww * (2.0f / 13.0f)) + txv;
    float gyv = (-1.0f + (float)hh * (2.0f / 13.0f)) + tyv;
    float pxv = (gxv + 1.0f) * 0.5f * 13.0f;
    float pyv = (gyv + 1.0f) * 0.5f * 13.0f;
    float x0f = floorf(pxv), y0f = floorf(pyv);
    int x0 = (int)x0f, y0 = (int)y0f;
    float wx = pxv - x0f, wy = pyv - y0f;
    auto samp = [&](int yi, int xi) -> float {
      if (yi < 4 || yi >= 9 || xi < 4 || xi >= 9) return 0.0f;
      return kern_s[p * 25 + (yi - 4) * 5 + (xi - 4)];
    };
    float kt = samp(y0, x0) * (1.0f - wy) * (1.0f - wx) +
               samp(y0, x0 + 1) * (1.0f - wy) * wx +
               samp(y0 + 1, x0) * wy * (1.0f - wx) +
               samp(y0 + 1, x0 + 1) * wy * wx;
    wk[idx] = wavg_s[98 + p] * kt;
  }
}

// ---------------- splat (batch-decoded) ----------------
__global__ __launch_bounds__(256) void k_splat(const float* __restrict__ feat,
                                               const float* __restrict__ wk,
                                               unsigned short* __restrict__ gfh,
                                               unsigned short* __restrict__ gfl) {
  __shared__ float fs[64 * 49];
  __shared__ float wks[49 * 196];
  const int t = threadIdx.x;
  const int b = blockIdx.x >> 8;
  const int rem = blockIdx.x & 255;
  const int ry = rem >> 4, rx = rem & 15;
  const float* featb = feat + (size_t)b * 64 * kP1;
  for (int idx = t; idx < 64 * 49; idx += 256) {
    int ci = idx / 49, p = idx % 49;
    int gy = ry * 7 + p / 7, gx = rx * 7 + p % 7;
    fs[idx] = featb[((size_t)ci * kH1 + gy) * kH1 + gx];
  }
  for (int idx = t; idx < 49 * 196; idx += 256) wks[idx] = wk[idx];
  __syncthreads();
  const int ci = t & 63;
  const int s = t >> 6;
  const int h0 = (s >> 1) * 7, w0 = (s & 1) * 7;
  float acc[49];
#pragma unroll
  for (int i = 0; i < 49; ++i) acc[i] = 0.0f;
  for (int p = 0; p < 49; ++p) {
    float f = fs[ci * 49 + p];
#pragma unroll
    for (int i = 0; i < 7; ++i)
#pragma unroll
      for (int j = 0; j < 7; ++j)
        acc[i * 7 + j] += f * wks[p * 196 + (h0 + i) * 14 + (w0 + j)];
  }
#pragma unroll
  for (int i = 0; i < 7; ++i)
#pragma unroll
    for (int j = 0; j < 7; ++j) {
      int Y = ry * 14 + h0 + i;
      int X = rx * 14 + w0 + j;
      float v = fminf(fmaxf(acc[i * 7 + j], 0.0f), 1.0f);
      unsigned short hi = f2bf(v);
      unsigned short lo = f2bf(v - bf2f(hi));
      size_t o = ((size_t)(b * kQ + Y * kH2 + X)) * 64 + ci;
      gfh[o] = hi;
      gfl[o] = lo;
    }
}

// ---------------- conv2: bf16x3 MFMA implicit GEMM, wave tile M=64 x N=128 ----------------
// Round 14: r13 counters show the K-loop is LDS-bound (A-reads 13.8K cyc vs
// MFMA 8.4K per block). Widening N/wave 64->128 (acc[4][8]) halves A-reads per
// FLOP (6.9K < 8.4K). Free VGPR alloc (no min-waves: r9 spill lesson).
__global__ __launch_bounds__(256) void k_conv2_mfma(
    const unsigned short* __restrict__ gfh, const unsigned short* __restrict__ gfl,
    const unsigned short* __restrict__ wph, const unsigned short* __restrict__ wpl,
    const float* __restrict__ coef_b, const float* __restrict__ freq_b,
    unsigned short* __restrict__ outp) {     // fp16 [NB*224*224][512]
  __shared__ __attribute__((aligned(16))) char Asb[2 * 180 * 144];  // 51,840 B
  const int t = threadIdx.x;
  const int b = blockIdx.x / 784;
  const int blk = blockIdx.x % 784;
  const int nb = blk & 1;
  const int mt = blk >> 1;
  const int ty = mt / 28, tx = mt % 28;
  const int py0 = ty * 16, px0 = tx * 8;

  for (int idx = t; idx < 2880; idx += 256) {
    int plane = idx >= 1440;
    int r2 = plane ? idx - 1440 : idx;
    int p = r2 >> 3, c8 = r2 & 7;
    int pr = p / 10, pc = p % 10;
    int gy = py0 - 1 + pr, gx = px0 - 1 + pc;
    uint4 u = make_uint4(0u, 0u, 0u, 0u);
    if (gy >= 0 && gy < kH2 && gx >= 0 && gx < kH2) {
      const unsigned short* src = (plane ? gfl : gfh) +
          ((size_t)(b * kQ + gy * kH2 + gx)) * 64 + c8 * 8;
      u = *(const uint4*)src;
    }
    *(uint4*)(Asb + plane * 25920 + p * 144 + c8 * 16) = u;
  }
  __syncthreads();

  const int w = t >> 6, lane = t & 63;
  const int quad = lane >> 4, ml = lane & 15;
  const int mh = w & 1;            // M-half (pixels mh*64 .. +64)
  const int nh = w >> 1;           // N-half within this nb (128 co)
  const unsigned int bvoff = (unsigned int)lane * 16u;

  f4v acc[4][8];
#pragma unroll
  for (int i = 0; i < 4; ++i)
#pragma unroll
    for (int j = 0; j < 8; ++j) acc[i][j] = (f4v){0.0f, 0.0f, 0.0f, 0.0f};

#pragma unroll
  for (int kk = 0; kk < 9; ++kk) {
    const int ky = kk / 3, kx = kk % 3;
#pragma unroll
    for (int cs = 0; cs < 2; ++cs) {
      const int kstep = kk * 2 + cs;
      s8v Bh[8], Bl[8];
#pragma unroll
      for (int j = 0; j < 8; ++j) {
        unsigned int off = ((unsigned int)((nb * 16 + nh * 8 + j) * 18 + kstep)) * 1024u + bvoff;
        Bh[j] = *(const s8v*)((const char*)wph + off);
        Bl[j] = *(const s8v*)((const char*)wpl + off);
      }
#pragma unroll
      for (int i = 0; i < 4; ++i) {
        const int aoff = ((mh * 8 + 2 * i + (ml >> 3) + ky) * 10 + (ml & 7) + kx) * 144 +
                         cs * 64 + quad * 16;
        s8v Ah = *(const s8v*)(Asb + aoff);
        s8v Al = *(const s8v*)(Asb + 25920 + aoff);
#pragma unroll
        for (int j = 0; j < 8; ++j) {
          acc[i][j] = __builtin_amdgcn_mfma_f32_16x16x32_bf16(Ah, Bh[j], acc[i][j], 0, 0, 0);
          acc[i][j] = __builtin_amdgcn_mfma_f32_16x16x32_bf16(Al, Bh[j], acc[i][j], 0, 0, 0);
          acc[i][j] = __builtin_amdgcn_mfma_f32_16x16x32_bf16(Ah, Bl[j], acc[i][j], 0, 0, 0);
        }
      }
    }
  }

  // ---- epilogue via LDS (16-pixel chunks), fp16 nt stores ----
  float bj[8];
#pragma unroll
  for (int j = 0; j < 8; ++j) {
    int co = nb * 256 + nh * 128 + j * 16 + ml;
    bj[j] = (co < 256) ? coef_b[co] : freq_b[co - 256];
  }
  __syncthreads();               // A-tile dead; reuse as staging
  float* Ls = (float*)Asb;       // [16 pixels][268 floats] = 17,152 B
  const int pq = t >> 4;
  const int ts2 = t & 15;
#pragma unroll
  for (int c = 0; c < 8; ++c) {
    if ((c >> 2) == mh) {
      const int i = c & 3;
#pragma unroll
      for (int j = 0; j < 8; ++j)
#pragma unroll
        for (int reg = 0; reg < 4; ++reg)
          Ls[(quad * 4 + reg) * 268 + nh * 128 + j * 16 + ml] = acc[i][j][reg] + bj[j];
    }
    __syncthreads();
    const int m = c * 16 + pq;
    const int Y = py0 + (m >> 3), X = px0 + (m & 7);
    unsigned short* orow = outp + ((size_t)(b * kQ + Y * kH2 + X)) * 512 + nb * 256;
    const float* lrow = Ls + pq * 268;
#pragma unroll
    for (int u = 0; u < 2; ++u) {
      float4 a = *(const float4*)(lrow + ts2 * 16 + u * 8);
      float4 bb = *(const float4*)(lrow + ts2 * 16 + u * 8 + 4);
      u4v v;
      v.x = (unsigned)f2h(a.x) | ((unsigned)f2h(a.y) << 16);
      v.y = (unsigned)f2h(a.z) | ((unsigned)f2h(a.w) << 16);
      v.z = (unsigned)f2h(bb.x) | ((unsigned)f2h(bb.y) << 16);
      v.w = (unsigned)f2h(bb.z) | ((unsigned)f2h(bb.w) << 16);
      __builtin_nontemporal_store(v, (u4v*)(orow + ts2 * 16 + u * 8));
    }
    __syncthreads();
  }
}

// ---------------- fused query: wave tile M=16 x N=128 (round 14) ----------------
// Same LDS-traffic argument as conv2: acc[8] (32 VGPR) + B[16] keeps VGPR ~130,
// LDS A-reads halve; 32-query blocks (4 blocks/CU).
__global__ __launch_bounds__(256) void k_query_mfma(
    const unsigned short* __restrict__ cfh,
    const float* __restrict__ coord,
    const float* __restrict__ cell, const float* __restrict__ phw,
    const unsigned short* __restrict__ wmlp,   // [2][hi/lo][65536]
    const float* __restrict__ b1, const float* __restrict__ b2,
    const float* __restrict__ w3, const float* __restrict__ b3,
    float* __restrict__ out, int q_base, size_t cf_stride) {
  __shared__ __attribute__((aligned(16))) char Xs[2 * 32 * 264 * 2];  // 33,792 B
  constexpr int ROW = 264 * 2;
  constexpr int PLANE = 32 * 264 * 2;
  const int t = threadIdx.x;

  // ---- phase 1: gather + basis (8 threads per query, 32 queries) ----
  {
    const int tq = t >> 3, ts = t & 7;
    const int qg = q_base + blockIdx.x * 32 + tq;
    const int b = qg / kQ;
    float gy = coord[(size_t)qg * 2 + 0];
    float gx = coord[(size_t)qg * 2 + 1];
    float fx = ((gx + 1.0f) * 224.0f - 1.0f) * 0.5f;
    float fy = ((gy + 1.0f) * 224.0f - 1.0f) * 0.5f;
    int ix = (int)rintf(fx);
    int iy = (int)rintf(fy);
    bool ok = (ix >= 0) && (ix < 224) && (iy >= 0) && (iy < 224);
    int ixc = min(max(ix, 0), 223);
    int iyc = min(max(iy, 0), 223);
    float m = ok ? 1.0f : 0.0f;
    float qcy = ok ? (-1.0f + (1.0f / 224.0f) + (2.0f / 224.0f) * (float)iyc) : 0.0f;
    float qcx = ok ? (-1.0f + (1.0f / 224.0f) + (2.0f / 224.0f) * (float)ixc) : 0.0f;
    float rel0 = (gy - qcy) * 224.0f;
    float rel1 = (gx - qcx) * 224.0f;
    float rc0 = cell[(size_t)qg * 2 + 0] * 224.0f;
    float rc1 = cell[(size_t)qg * 2 + 1] * 224.0f;
    const unsigned short* base = cfh + (size_t)b * cf_stride +
                                 (((size_t)iyc * kH2 + ixc) * 512);
    unsigned short ch_[8], cl_[8], sh_[8], sl_[8];
#pragma unroll
    for (int u = 0; u < 4; ++u) {
      const int k4 = ts * 16 + u * 4;
      ushort4 clo = *(const ushort4*)(base + k4);
      ushort4 chi = *(const ushort4*)(base + 128 + k4);
      ushort4 f0 = *(const ushort4*)(base + 256 + 2 * k4);
      ushort4 f1 = *(const ushort4*)(base + 256 + 2 * k4 + 4);
      float fr[8] = {h2f(f0.x), h2f(f0.y), h2f(f0.z), h2f(f0.w),
                     h2f(f1.x), h2f(f1.y), h2f(f1.z), h2f(f1.w)};
      float cl4[4] = {h2f(clo.x), h2f(clo.y), h2f(clo.z), h2f(clo.w)};
      float ch4[4] = {h2f(chi.x), h2f(chi.y), h2f(chi.z), h2f(chi.w)};
#pragma unroll
      for (int e = 0; e < 4; ++e) {
        const int k = k4 + e;
        float ph = rc0 * phw[2 * k] + rc1 * phw[2 * k + 1];
        float s = m * (fr[2 * e] * rel0 + fr[2 * e + 1] * rel1) + ph;
        float sv, cv;
        sincospif(s, &sv, &cv);
        float xc = m * cl4[e] * cv;
        float xsn = m * ch4[e] * sv;
        const int sl = (u & 1) * 4 + e;
        unsigned short h1_ = f2bf(xc);
        ch_[sl] = h1_; cl_[sl] = f2bf(xc - bf2f(h1_));
        unsigned short h2_ = f2bf(xsn);
        sh_[sl] = h2_; sl_[sl] = f2bf(xsn - bf2f(h2_));
      }
      if (u & 1) {
        const int kb = ts * 16 + (u - 1) * 4;
        uint4 v;
        v.x = (unsigned)ch_[0] | ((unsigned)ch_[1] << 16);
        v.y = (unsigned)ch_[2] | ((unsigned)ch_[3] << 16);
        v.z = (unsigned)ch_[4] | ((unsigned)ch_[5] << 16);
        v.w = (unsigned)ch_[6] | ((unsigned)ch_[7] << 16);
        *(uint4*)(Xs + tq * ROW + kb * 2) = v;
        v.x = (unsigned)cl_[0] | ((unsigned)cl_[1] << 16);
        v.y = (unsigned)cl_[2] | ((unsigned)cl_[3] << 16);
        v.z = (unsigned)cl_[4] | ((unsigned)cl_[5] << 16);
        v.w = (unsigned)cl_[6] | ((unsigned)cl_[7] << 16);
        *(uint4*)(Xs + PLANE + tq * ROW + kb * 2) = v;
        v.x = (unsigned)sh_[0] | ((unsigned)sh_[1] << 16);
        v.y = (unsigned)sh_[2] | ((unsigned)sh_[3] << 16);
        v.z = (unsigned)sh_[4] | ((unsigned)sh_[5] << 16);
        v.w = (unsigned)sh_[6] | ((unsigned)sh_[7] << 16);
        *(uint4*)(Xs + tq * ROW + (128 + kb) * 2) = v;
        v.x = (unsigned)sl_[0] | ((unsigned)sl_[1] << 16);
        v.y = (unsigned)sl_[2] | ((unsigned)sl_[3] << 16);
        v.z = (unsigned)sl_[4] | ((unsigned)sl_[5] << 16);
        v.w = (unsigned)sl_[6] | ((unsigned)sl_[7] << 16);
        *(uint4*)(Xs + PLANE + tq * ROW + (128 + kb) * 2) = v;
      }
    }
  }
  __syncthreads();

  const int w = t >> 6, lane = t & 63;
  const int quad = lane >> 4, ml = lane & 15;
  const int mh = w & 1;           // query half (rows mh*16..+16)
  const int nh = w >> 1;          // N half (128 cols)
  const unsigned int bvoff = (unsigned int)lane * 16u;

#pragma unroll
  for (int layer = 0; layer < 2; ++layer) {
    const unsigned short* wb = wmlp + layer * 131072;
    f4v acc[8];
#pragma unroll
    for (int j = 0; j < 8; ++j) acc[j] = (f4v){0.0f, 0.0f, 0.0f, 0.0f};
#pragma unroll
    for (int kstep = 0; kstep < 8; ++kstep) {
      s8v Bh[8], Bl[8];
#pragma unroll
      for (int j = 0; j < 8; ++j) {
        unsigned int off = (unsigned int)((nh * 8 + j) * 8 + kstep) * 1024u + bvoff;
        Bh[j] = *(const s8v*)((const char*)wb + off);
        Bl[j] = *(const s8v*)((const char*)(wb + 65536) + off);
      }
      const int aoff = (mh * 16 + ml) * ROW + (kstep * 32 + quad * 8) * 2;
      s8v Ah = *(const s8v*)(Xs + aoff);
      s8v Al = *(const s8v*)(Xs + PLANE + aoff);
#pragma unroll
      for (int j = 0; j < 8; ++j) {
        acc[j] = __builtin_amdgcn_mfma_f32_16x16x32_bf16(Ah, Bh[j], acc[j], 0, 0, 0);
        acc[j] = __builtin_amdgcn_mfma_f32_16x16x32_bf16(Al, Bh[j], acc[j], 0, 0, 0);
        acc[j] = __builtin_amdgcn_mfma_f32_16x16x32_bf16(Ah, Bl[j], acc[j], 0, 0, 0);
      }
    }
    __syncthreads();
    const float* bs = layer ? b2 : b1;
    float bj[8];
#pragma unroll
    for (int j = 0; j < 8; ++j) bj[j] = bs[nh * 128 + j * 16 + ml];
    if (layer == 0) {
#pragma unroll
      for (int j = 0; j < 8; ++j)
#pragma unroll
        for (int reg = 0; reg < 4; ++reg) {
          int m = mh * 16 + quad * 4 + reg;
          int n = nh * 128 + j * 16 + ml;
          float v = fmaxf(acc[j][reg] + bj[j], 0.0f);
          unsigned short hi = f2bf(v);
          unsigned short lo = f2bf(v - bf2f(hi));
          *(unsigned short*)(Xs + m * ROW + n * 2) = hi;
          *(unsigned short*)(Xs + PLANE + m * ROW + n * 2) = lo;
        }
    } else {
#pragma unroll
      for (int j = 0; j < 8; ++j)
#pragma unroll
        for (int reg = 0; reg < 4; ++reg) {
          int m = mh * 16 + quad * 4 + reg;
          int n = nh * 128 + j * 16 + ml;
          float v = fmaxf(acc[j][reg] + bj[j], 0.0f);
          *(float*)(Xs + ((size_t)m * 264 + n) * 4) = v;
        }
    }
    __syncthreads();
  }

  // ---- phase 3: 3-wide output layer (8 threads per query) ----
  {
    const int tq = t >> 3, ts = t & 7;
    const float* xr = (const float*)(Xs + (size_t)tq * 264 * 4);
    float c0 = 0, c1 = 0, c2 = 0;
    for (int k = ts * 32; k < ts * 32 + 32; ++k) {
      float xv = xr[k];
      c0 += xv * w3[k];
      c1 += xv * w3[256 + k];
      c2 += xv * w3[512 + k];
    }
    c0 += __shfl_down(c0, 4, 8); c0 += __shfl_down(c0, 2, 8); c0 += __shfl_down(c0, 1, 8);
    c1 += __shfl_down(c1, 4, 8); c1 += __shfl_down(c1, 2, 8); c1 += __shfl_down(c1, 1, 8);
    c2 += __shfl_down(c2, 4, 8); c2 += __shfl_down(c2, 2, 8); c2 += __shfl_down(c2, 1, 8);
    if (ts == 0) {
      const int qg = q_base + blockIdx.x * 32 + tq;
      float* o = out + (size_t)qg * 3;
      o[0] = c0 + b3[0];
      o[1] = c1 + b3[1];
      o[2] = c2 + b3[2];
    }
  }
}

// ---------------- launch ----------------
extern "C" void kernel_launch(void* const* d_in, const int* in_sizes, int n_in,
                              void* d_out, int out_size, void* d_ws, size_t ws_size,
                              hipStream_t stream) {
  (void)in_sizes; (void)n_in; (void)out_size;
  const float* feat   = (const float*)d_in[0];
  const float* coord  = (const float*)d_in[1];
  const float* cell   = (const float*)d_in[2];
  const float* cls_w1 = (const float*)d_in[3];
  const float* cls_b1 = (const float*)d_in[4];
  const float* cls_w2 = (const float*)d_in[5];
  const float* cls_b2 = (const float*)d_in[6];
  const float* sigx   = (const float*)d_in[7];
  const float* sigy   = (const float*)d_in[8];
  const float* opac   = (const float*)d_in[9];
  const float* rho    = (const float*)d_in[10];
  const float* coef_w = (const float*)d_in[11];
  const float* coef_b = (const float*)d_in[12];
  const float* freq_w = (const float*)d_in[13];
  const float* freq_b = (const float*)d_in[14];
  const float* phw    = (const float*)d_in[15];
  const float* w1     = (const float*)d_in[16];
  const float* b1     = (const float*)d_in[17];
  const float* w2     = (const float*)d_in[18];
  const float* b2     = (const float*)d_in[19];
  const float* w3     = (const float*)d_in[20];
  const float* b3     = (const float*)d_in[21];

  const bool big = ws_size >= A_TOTAL;
  char* ws = (char*)d_ws;
  const size_t wbase = big ? A_WBASE : B_WBASE;
  unsigned short* fbh = (unsigned short*)(ws + (big ? A_FBH : B_FBH));
  unsigned short* fbl = (unsigned short*)(ws + (big ? A_FBL : B_FBL));
  unsigned short* gfh = (unsigned short*)(ws + (big ? A_GFH : B_GFH));
  unsigned short* gfl = (unsigned short*)(ws + (big ? A_GFL : B_GFL));
  float* h_buf = (float*)(ws + (big ? A_H : B_H));
  unsigned short* cfb = (unsigned short*)(ws + (big ? A_CF : B_CF));
  unsigned short* wph = (unsigned short*)(ws + wbase + W_WPH);
  unsigned short* wpl = (unsigned short*)(ws + wbase + W_WPL);
  unsigned short* w1h = (unsigned short*)(ws + wbase + W_W1H);
  unsigned short* w1l = (unsigned short*)(ws + wbase + W_W1L);
  unsigned short* wmlp = (unsigned short*)(ws + wbase + W_WMLP);
  float* wsums = (float*)(ws + wbase + W_WSUM);
  float* wk    = (float*)(ws + wbase + W_WK);
  float* outp  = (float*)d_out;

  hipLaunchKernelGGL(k_init, dim3(1), dim3(256), 0, stream, wsums);
  hipLaunchKernelGGL(k_prepw, dim3(1152), dim3(256), 0, stream, coef_w, freq_w, wph, wpl);
  hipLaunchKernelGGL(k_prepw1, dim3(144), dim3(256), 0, stream, cls_w1, w1h, w1l);
  hipLaunchKernelGGL(k_prepmlp, dim3(512), dim3(256), 0, stream, w1, w2, wmlp);
  hipLaunchKernelGGL(k_prepfeat, dim3(784), dim3(256), 0, stream, feat, fbh, fbl);
  hipLaunchKernelGGL(k_conv1_mfma, dim3(392), dim3(256), 0, stream,
                     fbh, fbl, w1h, w1l, cls_b1, h_buf);
  hipLaunchKernelGGL(k_wavg, dim3(196), dim3(256), 0, stream,
                     h_buf, cls_w2, cls_b2, sigx, sigy, opac, rho, wsums);
  hipLaunchKernelGGL(k_finalize, dim3(1), dim3(256), 0, stream, wsums, wk);

  if (big) {
    hipLaunchKernelGGL(k_splat, dim3(4 * 256), dim3(256), 0, stream, feat, wk, gfh, gfl);
    hipLaunchKernelGGL(k_conv2_mfma, dim3(4 * 784), dim3(256), 0, stream,
                       gfh, gfl, wph, wpl, coef_b, freq_b, cfb);
    hipLaunchKernelGGL(k_query_mfma, dim3(4 * 1568), dim3(256), 0, stream,
                       cfb, coord, cell, phw, wmlp, b1, b2, w3, b3, outp,
                       0, (size_t)kQ * 512);
  } else {
    for (int b = 0; b < kB; ++b) {
      const float* feat_b = feat + (size_t)b * 64 * kP1;
      hipLaunchKernelGGL(k_splat, dim3(256), dim3(256), 0, stream, feat_b, wk, gfh, gfl);
      hipLaunchKernelGGL(k_conv2_mfma, dim3(784), dim3(256), 0, stream,
                         gfh, gfl, wph, wpl, coef_b, freq_b, cfb);
      hipLaunchKernelGGL(k_query_mfma, dim3(1568), dim3(256), 0, stream,
                         cfb, coord, cell, phw, wmlp, b1, b2, w3, b3, outp,
                         b * kQ, (size_t)0);
    }
  }
}

// Round 15
// 797.627 us; speedup vs baseline: 1.1329x; 1.1329x over previous
//
#include <hip/hip_runtime.h>
#include <hip/hip_fp16.h>
#include <math.h>

// ---------------- problem constants ----------------
namespace {
constexpr int kB   = 4;
constexpr int kNG  = 100;
constexpr int kH1  = 112;            // feat H/W
constexpr int kH2  = 224;            // upscaled H/W
constexpr int kQ   = kH2 * kH2;      // 50176 queries per batch image
constexpr int kP1  = kH1 * kH1;      // 12544 pixels per image (feat res)

// ---- path B (per-image loop) workspace layout, ~79 MB ----
constexpr size_t B_FBH  = 0;
constexpr size_t B_FBL  = 6422528;
constexpr size_t B_GFH  = 0;
constexpr size_t B_GFL  = 6422528;
constexpr size_t B_H    = 12845056;
constexpr size_t B_CF   = 25690112;
constexpr size_t B_WBASE= B_CF + 51380224;

// ---- path A (batched) workspace layout, ~259 MB ----
constexpr size_t A_FBH  = 0;
constexpr size_t A_FBL  = 6422528;
constexpr size_t A_H    = 12845056;
constexpr size_t A_GFH  = 0;
constexpr size_t A_GFL  = 25690112;
constexpr size_t A_CF   = 51380224;
constexpr size_t A_WBASE= A_CF + 205520896;
constexpr size_t A_TOTAL= A_WBASE + 1893376;

// weight region offsets (relative to WBASE)
constexpr size_t W_WPH  = 0;
constexpr size_t W_WPL  = 589824;
constexpr size_t W_W1H  = 1179648;
constexpr size_t W_W1L  = 1253376;
constexpr size_t W_WMLP = 1327104;
constexpr size_t W_WSUM = 1851392;
constexpr size_t W_WK   = 1852416;
}  // namespace

using s8v = __attribute__((ext_vector_type(8))) short;   // 8 bf16 (4 VGPRs)
using f4v = __attribute__((ext_vector_type(4))) float;   // MFMA acc
using u4v = __attribute__((ext_vector_type(4))) unsigned int;

__device__ __forceinline__ unsigned short f2bf(float f) {
  unsigned int u = __float_as_uint(f);
  unsigned int r = u + 0x7fffu + ((u >> 16) & 1u);
  return (unsigned short)(r >> 16);
}
__device__ __forceinline__ float bf2f(unsigned short h) {
  return __uint_as_float((unsigned int)h << 16);
}
__device__ __forceinline__ unsigned short f2h(float f) {
  return __builtin_bit_cast(unsigned short, __float2half(f));
}
__device__ __forceinline__ float h2f(unsigned short u) {
  return __half2float(__builtin_bit_cast(__half, u));
}

// ---------------- tiny helpers ----------------
__global__ void k_init(float* wsums) {
  int t = threadIdx.x;
  if (t < 196) wsums[t] = 0.0f;
}

__global__ __launch_bounds__(256) void k_prepfeat(const float* __restrict__ feat,
                                                  unsigned short* __restrict__ fbh,
                                                  unsigned short* __restrict__ fbl) {
  __shared__ float ls[64 * 65];
  const int t = threadIdx.x;
  const int b = blockIdx.x / 196;
  const int seg = blockIdx.x % 196;
  const int pixbase = seg * 64;
  for (int idx = t; idx < 4096; idx += 256) {
    int ci = idx >> 6, px = idx & 63;
    ls[px * 65 + ci] = feat[((size_t)(b * 64 + ci)) * kP1 + pixbase + px];
  }
  __syncthreads();
  for (int idx = t; idx < 4096; idx += 256) {
    int px = idx >> 6, ci = idx & 63;
    float v = ls[px * 65 + ci];
    unsigned short hi = f2bf(v);
    unsigned short lo = f2bf(v - bf2f(hi));
    size_t o = ((size_t)(b * kP1 + pixbase + px)) * 64 + ci;
    fbh[o] = hi;
    fbl[o] = lo;
  }
}

__global__ void k_prepw(const float* __restrict__ cw, const float* __restrict__ fw,
                        unsigned short* __restrict__ wph, unsigned short* __restrict__ wpl) {
  int e = blockIdx.x * 256 + threadIdx.x;   // 512*576
  int co = e / 576, k = e % 576;
  int ci = k & 63, kk = k >> 6;
  float v = (co < 256) ? cw[co * 576 + ci * 9 + kk] : fw[(co - 256) * 576 + ci * 9 + kk];
  unsigned short hi = f2bf(v);
  unsigned short lo = f2bf(v - bf2f(hi));
  int n16 = co >> 4, nl = co & 15;
  int kstep = k >> 5, kr = k & 31;
  int dst = ((n16 * 18 + kstep) * 64 + (kr >> 3) * 16 + nl) * 8 + (kr & 7);
  wph[dst] = hi;
  wpl[dst] = lo;
}

__global__ void k_prepw1(const float* __restrict__ w1src,
                         unsigned short* __restrict__ wph, unsigned short* __restrict__ wpl) {
  int e = blockIdx.x * 256 + threadIdx.x;   // 64*576
  int co = e / 576, k = e % 576;
  int ci = k & 63, kk = k >> 6;
  float v = w1src[co * 576 + ci * 9 + kk];
  unsigned short hi = f2bf(v);
  unsigned short lo = f2bf(v - bf2f(hi));
  int n16 = co >> 4, nl = co & 15;
  int kstep = k >> 5, kr = k & 31;
  int dst = ((n16 * 18 + kstep) * 64 + (kr >> 3) * 16 + nl) * 8 + (kr & 7);
  wph[dst] = hi;
  wpl[dst] = lo;
}

__global__ void k_prepmlp(const float* __restrict__ w1, const float* __restrict__ w2,
                          unsigned short* __restrict__ wp) {
  int e = blockIdx.x * 256 + threadIdx.x;   // 131072
  int mat = e >> 16, idx = e & 65535;
  int j = idx >> 8, k = idx & 255;
  float v = (mat ? w2 : w1)[j * 256 + k];
  unsigned short hi = f2bf(v);
  unsigned short lo = f2bf(v - bf2f(hi));
  int n16 = j >> 4, nl = j & 15;
  int kstep = k >> 5, kr = k & 31;
  int dst = ((n16 * 8 + kstep) * 64 + (kr >> 3) * 16 + nl) * 8 + (kr & 7);
  wp[mat * 131072 + dst] = hi;
  wp[mat * 131072 + 65536 + dst] = lo;
}

// ---------------- conv1 as bf16x3 MFMA implicit GEMM ----------------
__global__ __launch_bounds__(256) void k_conv1_mfma(
    const unsigned short* __restrict__ fbh, const unsigned short* __restrict__ fbl,
    const unsigned short* __restrict__ wph, const unsigned short* __restrict__ wpl,
    const float* __restrict__ bias, float* __restrict__ outp) {
  __shared__ __attribute__((aligned(16))) char Asb[2 * 180 * 144];
  const int t = threadIdx.x;
  const int blk = blockIdx.x;          // 392
  const int b = blk / 98;
  const int mt = blk % 98;
  const int ty = mt / 14, tx = mt % 14;
  const int py0 = ty * 16, px0 = tx * 8;

  for (int idx = t; idx < 2880; idx += 256) {
    int plane = idx >= 1440;
    int r2 = plane ? idx - 1440 : idx;
    int p = r2 >> 3, c8 = r2 & 7;
    int pr = p / 10, pc = p % 10;
    int gy = py0 - 1 + pr, gx = px0 - 1 + pc;
    uint4 u = make_uint4(0u, 0u, 0u, 0u);
    if (gy >= 0 && gy < kH1 && gx >= 0 && gx < kH1) {
      const unsigned short* src = (plane ? fbl : fbh) +
          ((size_t)(b * kP1 + gy * kH1 + gx)) * 64 + c8 * 8;
      u = *(const uint4*)src;
    }
    *(uint4*)(Asb + plane * 25920 + p * 144 + c8 * 16) = u;
  }
  __syncthreads();

  const int w = t >> 6, lane = t & 63;
  const int quad = lane >> 4, ml = lane & 15;

  f4v acc[8];
#pragma unroll
  for (int i = 0; i < 8; ++i) acc[i] = (f4v){0.0f, 0.0f, 0.0f, 0.0f};

  const unsigned int bvoff = (unsigned int)lane * 16u;
#pragma unroll
  for (int kk = 0; kk < 9; ++kk) {
    const int ky = kk / 3, kx = kk % 3;
#pragma unroll
    for (int cs = 0; cs < 2; ++cs) {
      const int kstep = kk * 2 + cs;
      unsigned int off = ((unsigned int)(w * 18 + kstep)) * 1024u + bvoff;
      s8v Bh = *(const s8v*)((const char*)wph + off);
      s8v Bl = *(const s8v*)((const char*)wpl + off);
#pragma unroll
      for (int i = 0; i < 8; ++i) {
        const int aoff = ((2 * i + (ml >> 3) + ky) * 10 + (ml & 7) + kx) * 144 + cs * 64 + quad * 16;
        s8v Ah = *(const s8v*)(Asb + aoff);
        s8v Al = *(const s8v*)(Asb + 25920 + aoff);
        acc[i] = __builtin_amdgcn_mfma_f32_16x16x32_bf16(Ah, Bh, acc[i], 0, 0, 0);
        acc[i] = __builtin_amdgcn_mfma_f32_16x16x32_bf16(Al, Bh, acc[i], 0, 0, 0);
        acc[i] = __builtin_amdgcn_mfma_f32_16x16x32_bf16(Ah, Bl, acc[i], 0, 0, 0);
      }
    }
  }

  const float bv = bias[w * 16 + ml];
#pragma unroll
  for (int i = 0; i < 8; ++i)
#pragma unroll
    for (int reg = 0; reg < 4; ++reg) {
      int m = i * 16 + quad * 4 + reg;
      int Y = py0 + (m >> 3), X = px0 + (m & 7);
      outp[((size_t)(b * kP1 + Y * kH1 + X)) * 64 + w * 16 + ml] =
          fmaxf(acc[i][reg] + bv, 0.0f);
    }
}

// ---------------- 1x1 conv + softmax + weighted sums ----------------
__global__ __launch_bounds__(256) void k_wavg(
    const float* __restrict__ h, const float* __restrict__ w2, const float* __restrict__ b2,
    const float* __restrict__ sx, const float* __restrict__ sy,
    const float* __restrict__ op, const float* __restrict__ rho,
    float* __restrict__ wsums) {
  __shared__ float w2s[kNG * 64];
  __shared__ float prm[4 * kNG];
  __shared__ float b2s[kNG];
  __shared__ float pl[196];
  const int t = threadIdx.x;
  for (int i = t; i < kNG * 64; i += 256) w2s[i] = w2[i];
  if (t < kNG) {
    prm[t] = sx[t];
    prm[kNG + t] = sy[t];
    prm[2 * kNG + t] = op[t];
    prm[3 * kNG + t] = rho[t];
    b2s[t] = b2[t];
  }
  if (t < 196) pl[t] = 0.0f;
  __syncthreads();
  const int id = blockIdx.x * 256 + t;
  float hreg[64];
  const float4* hp = (const float4*)(h + (size_t)id * 64);
#pragma unroll
  for (int i = 0; i < 16; ++i) {
    float4 v = hp[i];
    hreg[4 * i] = v.x; hreg[4 * i + 1] = v.y;
    hreg[4 * i + 2] = v.z; hreg[4 * i + 3] = v.w;
  }
  float S = 0, Sx = 0, Sy = 0, So = 0, Sr = 0;
  for (int g = 0; g < kNG; ++g) {
    float d = b2s[g];
    const float4* wp = (const float4*)(w2s + g * 64);
#pragma unroll
    for (int i = 0; i < 16; ++i) {
      float4 w = wp[i];
      d += hreg[4 * i] * w.x + hreg[4 * i + 1] * w.y +
           hreg[4 * i + 2] * w.z + hreg[4 * i + 3] * w.w;
    }
    float e = expf(d);
    S += e;
    Sx += e * prm[g];
    Sy += e * prm[kNG + g];
    So += e * prm[2 * kNG + g];
    Sr += e * prm[3 * kNG + g];
  }
  const int rem = id % (kH1 * kH1);
  const int p = ((rem / kH1) % 7) * 7 + ((rem % kH1) % 7);
  const float inv = 1.0f / S;
  atomicAdd(&pl[p], Sx * inv);
  atomicAdd(&pl[49 + p], Sy * inv);
  atomicAdd(&pl[98 + p], So * inv);
  atomicAdd(&pl[147 + p], Sr * inv);
  __syncthreads();
  if (t < 196) atomicAdd(&wsums[t], pl[t]);
}

// ---------------- build wk[p][h][w] ----------------
__global__ __launch_bounds__(256) void k_finalize(const float* __restrict__ wsums,
                                                  float* __restrict__ wk) {
  __shared__ float kern_s[49 * 25];
  __shared__ float wavg_s[196];
  const int t = threadIdx.x;
  if (t < 196) wavg_s[t] = wsums[t] * (1.0f / 1024.0f);
  __syncthreads();
  if (t < 49) {
    float wsx = wavg_s[t], wsy = wavg_s[49 + t], wr = wavg_s[147 + t];
    float c00 = wsx * wsx + 1e-5f;
    float c11 = wsy * wsy + 1e-5f;
    float c01 = wr * wsx * wsy;
    float det = c00 * c11 - c01 * c01;
    float i00 = c11 / det, i11 = c00 / det, i01 = -c01 / det;
    float nrm = 1.0f / (2.0f * 3.14159265358979323846f * sqrtf(det));
    float vals[25];
    float mx = -1e30f;
#pragma unroll
    for (int i = 0; i < 5; ++i) {
#pragma unroll
      for (int j = 0; j < 5; ++j) {
        float yv = -5.0f + 2.5f * (float)i;
        float xv = -5.0f + 2.5f * (float)j;
        float z = -0.5f * (i00 * xv * xv + 2.0f * i01 * xv * yv + i11 * yv * yv);
        float v = expf(z) * nrm;
        vals[i * 5 + j] = v;
        mx = fmaxf(mx, v);
      }
    }
#pragma unroll
    for (int k = 0; k < 25; ++k) kern_s[t * 25 + k] = vals[k] / mx;
  }
  __syncthreads();
  for (int idx = t; idx < 49 * 196; idx += 256) {
    const int p = idx / 196;
    const int hw = idx % 196;
    const int hh = hw / 14, ww = hw % 14;
    float txv = (0.5f - (float)(p / 7) / 7.0f) * 2.0f;
    float tyv = (0.5f - (float)(p % 7) / 7.0f) * 2.0f;
    float gxv = (-1.0f + (float)ww * (2.0f / 13.0f)) + txv;
    float gyv = (-1.0f + (float)hh * (2.0f / 13.0f)) + tyv;
    float pxv = (gxv + 1.0f) * 0.5f * 13.0f;
    float pyv = (gyv + 1.0f) * 0.5f * 13.0f;
    float x0f = floorf(pxv), y0f = floorf(pyv);
    int x0 = (int)x0f, y0 = (int)y0f;
    float wx = pxv - x0f, wy = pyv - y0f;
    auto samp = [&](int yi, int xi) -> float {
      if (yi < 4 || yi >= 9 || xi < 4 || xi >= 9) return 0.0f;
      return kern_s[p * 25 + (yi - 4) * 5 + (xi - 4)];
    };
    float kt = samp(y0, x0) * (1.0f - wy) * (1.0f - wx) +
               samp(y0, x0 + 1) * (1.0f - wy) * wx +
               samp(y0 + 1, x0) * wy * (1.0f - wx) +
               samp(y0 + 1, x0 + 1) * wy * wx;
    wk[idx] = wavg_s[98 + p] * kt;
  }
}

// ---------------- splat (batch-decoded) ----------------
__global__ __launch_bounds__(256) void k_splat(const float* __restrict__ feat,
                                               const float* __restrict__ wk,
                                               unsigned short* __restrict__ gfh,
                                               unsigned short* __restrict__ gfl) {
  __shared__ float fs[64 * 49];
  __shared__ float wks[49 * 196];
  const int t = threadIdx.x;
  const int b = blockIdx.x >> 8;
  const int rem = blockIdx.x & 255;
  const int ry = rem >> 4, rx = rem & 15;
  const float* featb = feat + (size_t)b * 64 * kP1;
  for (int idx = t; idx < 64 * 49; idx += 256) {
    int ci = idx / 49, p = idx % 49;
    int gy = ry * 7 + p / 7, gx = rx * 7 + p % 7;
    fs[idx] = featb[((size_t)ci * kH1 + gy) * kH1 + gx];
  }
  for (int idx = t; idx < 49 * 196; idx += 256) wks[idx] = wk[idx];
  __syncthreads();
  const int ci = t & 63;
  const int s = t >> 6;
  const int h0 = (s >> 1) * 7, w0 = (s & 1) * 7;
  float acc[49];
#pragma unroll
  for (int i = 0; i < 49; ++i) acc[i] = 0.0f;
  for (int p = 0; p < 49; ++p) {
    float f = fs[ci * 49 + p];
#pragma unroll
    for (int i = 0; i < 7; ++i)
#pragma unroll
      for (int j = 0; j < 7; ++j)
        acc[i * 7 + j] += f * wks[p * 196 + (h0 + i) * 14 + (w0 + j)];
  }
#pragma unroll
  for (int i = 0; i < 7; ++i)
#pragma unroll
    for (int j = 0; j < 7; ++j) {
      int Y = ry * 14 + h0 + i;
      int X = rx * 14 + w0 + j;
      float v = fminf(fmaxf(acc[i * 7 + j], 0.0f), 1.0f);
      unsigned short hi = f2bf(v);
      unsigned short lo = f2bf(v - bf2f(hi));
      size_t o = ((size_t)(b * kQ + Y * kH2 + X)) * 64 + ci;
      gfh[o] = hi;
      gfl[o] = lo;
    }
}

// ---------------- conv2: bf16x3 MFMA implicit GEMM, wave tile M=64 x N=128 ----------------
// r14 counters: this widening lifted conv2 out of the top-5 (~270 us batched).
// M=128 pixels/block amortizes the doubled B-fetch (unlike query, where the
// same change regressed — B-reuse asymmetry, r14 lesson).
__global__ __launch_bounds__(256) void k_conv2_mfma(
    const unsigned short* __restrict__ gfh, const unsigned short* __restrict__ gfl,
    const unsigned short* __restrict__ wph, const unsigned short* __restrict__ wpl,
    const float* __restrict__ coef_b, const float* __restrict__ freq_b,
    unsigned short* __restrict__ outp) {     // fp16 [NB*224*224][512]
  __shared__ __attribute__((aligned(16))) char Asb[2 * 180 * 144];  // 51,840 B
  const int t = threadIdx.x;
  const int b = blockIdx.x / 784;
  const int blk = blockIdx.x % 784;
  const int nb = blk & 1;
  const int mt = blk >> 1;
  const int ty = mt / 28, tx = mt % 28;
  const int py0 = ty * 16, px0 = tx * 8;

  for (int idx = t; idx < 2880; idx += 256) {
    int plane = idx >= 1440;
    int r2 = plane ? idx - 1440 : idx;
    int p = r2 >> 3, c8 = r2 & 7;
    int pr = p / 10, pc = p % 10;
    int gy = py0 - 1 + pr, gx = px0 - 1 + pc;
    uint4 u = make_uint4(0u, 0u, 0u, 0u);
    if (gy >= 0 && gy < kH2 && gx >= 0 && gx < kH2) {
      const unsigned short* src = (plane ? gfl : gfh) +
          ((size_t)(b * kQ + gy * kH2 + gx)) * 64 + c8 * 8;
      u = *(const uint4*)src;
    }
    *(uint4*)(Asb + plane * 25920 + p * 144 + c8 * 16) = u;
  }
  __syncthreads();

  const int w = t >> 6, lane = t & 63;
  const int quad = lane >> 4, ml = lane & 15;
  const int mh = w & 1;            // M-half (pixels mh*64 .. +64)
  const int nh = w >> 1;           // N-half within this nb (128 co)
  const unsigned int bvoff = (unsigned int)lane * 16u;

  f4v acc[4][8];
#pragma unroll
  for (int i = 0; i < 4; ++i)
#pragma unroll
    for (int j = 0; j < 8; ++j) acc[i][j] = (f4v){0.0f, 0.0f, 0.0f, 0.0f};

#pragma unroll
  for (int kk = 0; kk < 9; ++kk) {
    const int ky = kk / 3, kx = kk % 3;
#pragma unroll
    for (int cs = 0; cs < 2; ++cs) {
      const int kstep = kk * 2 + cs;
      s8v Bh[8], Bl[8];
#pragma unroll
      for (int j = 0; j < 8; ++j) {
        unsigned int off = ((unsigned int)((nb * 16 + nh * 8 + j) * 18 + kstep)) * 1024u + bvoff;
        Bh[j] = *(const s8v*)((const char*)wph + off);
        Bl[j] = *(const s8v*)((const char*)wpl + off);
      }
#pragma unroll
      for (int i = 0; i < 4; ++i) {
        const int aoff = ((mh * 8 + 2 * i + (ml >> 3) + ky) * 10 + (ml & 7) + kx) * 144 +
                         cs * 64 + quad * 16;
        s8v Ah = *(const s8v*)(Asb + aoff);
        s8v Al = *(const s8v*)(Asb + 25920 + aoff);
#pragma unroll
        for (int j = 0; j < 8; ++j) {
          acc[i][j] = __builtin_amdgcn_mfma_f32_16x16x32_bf16(Ah, Bh[j], acc[i][j], 0, 0, 0);
          acc[i][j] = __builtin_amdgcn_mfma_f32_16x16x32_bf16(Al, Bh[j], acc[i][j], 0, 0, 0);
          acc[i][j] = __builtin_amdgcn_mfma_f32_16x16x32_bf16(Ah, Bl[j], acc[i][j], 0, 0, 0);
        }
      }
    }
  }

  // ---- epilogue via LDS (16-pixel chunks), fp16 nt stores ----
  float bj[8];
#pragma unroll
  for (int j = 0; j < 8; ++j) {
    int co = nb * 256 + nh * 128 + j * 16 + ml;
    bj[j] = (co < 256) ? coef_b[co] : freq_b[co - 256];
  }
  __syncthreads();               // A-tile dead; reuse as staging
  float* Ls = (float*)Asb;       // [16 pixels][268 floats]
  const int pq = t >> 4;
  const int ts2 = t & 15;
#pragma unroll
  for (int c = 0; c < 8; ++c) {
    if ((c >> 2) == mh) {
      const int i = c & 3;
#pragma unroll
      for (int j = 0; j < 8; ++j)
#pragma unroll
        for (int reg = 0; reg < 4; ++reg)
          Ls[(quad * 4 + reg) * 268 + nh * 128 + j * 16 + ml] = acc[i][j][reg] + bj[j];
    }
    __syncthreads();
    const int m = c * 16 + pq;
    const int Y = py0 + (m >> 3), X = px0 + (m & 7);
    unsigned short* orow = outp + ((size_t)(b * kQ + Y * kH2 + X)) * 512 + nb * 256;
    const float* lrow = Ls + pq * 268;
#pragma unroll
    for (int u = 0; u < 2; ++u) {
      float4 a = *(const float4*)(lrow + ts2 * 16 + u * 8);
      float4 bb = *(const float4*)(lrow + ts2 * 16 + u * 8 + 4);
      u4v v;
      v.x = (unsigned)f2h(a.x) | ((unsigned)f2h(a.y) << 16);
      v.y = (unsigned)f2h(a.z) | ((unsigned)f2h(a.w) << 16);
      v.z = (unsigned)f2h(bb.x) | ((unsigned)f2h(bb.y) << 16);
      v.w = (unsigned)f2h(bb.z) | ((unsigned)f2h(bb.w) << 16);
      __builtin_nontemporal_store(v, (u4v*)(orow + ts2 * 16 + u * 8));
    }
    __syncthreads();
  }
}

// ---------------- fused query: r12/r13 config restored (M=32/wave, N=64/wave) ----------------
// r14's N=128 widening regressed query (B-reuse too low at M=32/block).
__global__ __launch_bounds__(256) void k_query_mfma(
    const unsigned short* __restrict__ cfh,
    const float* __restrict__ coord,
    const float* __restrict__ cell, const float* __restrict__ phw,
    const unsigned short* __restrict__ wmlp,   // [2][hi/lo][65536]
    const float* __restrict__ b1, const float* __restrict__ b2,
    const float* __restrict__ w3, const float* __restrict__ b3,
    float* __restrict__ out, int q_base, size_t cf_stride) {
  __shared__ __attribute__((aligned(16))) char Xs[2 * 32 * 264 * 2];  // 33,792 B
  constexpr int ROW = 264 * 2;
  constexpr int PLANE = 32 * 264 * 2;
  const int t = threadIdx.x;

  // ---- phase 1: gather + basis (8 threads per query, 32 queries) ----
  {
    const int tq = t >> 3, ts = t & 7;
    const int qg = q_base + blockIdx.x * 32 + tq;
    const int b = qg / kQ;
    float gy = coord[(size_t)qg * 2 + 0];
    float gx = coord[(size_t)qg * 2 + 1];
    float fx = ((gx + 1.0f) * 224.0f - 1.0f) * 0.5f;
    float fy = ((gy + 1.0f) * 224.0f - 1.0f) * 0.5f;
    int ix = (int)rintf(fx);
    int iy = (int)rintf(fy);
    bool ok = (ix >= 0) && (ix < 224) && (iy >= 0) && (iy < 224);
    int ixc = min(max(ix, 0), 223);
    int iyc = min(max(iy, 0), 223);
    float m = ok ? 1.0f : 0.0f;
    float qcy = ok ? (-1.0f + (1.0f / 224.0f) + (2.0f / 224.0f) * (float)iyc) : 0.0f;
    float qcx = ok ? (-1.0f + (1.0f / 224.0f) + (2.0f / 224.0f) * (float)ixc) : 0.0f;
    float rel0 = (gy - qcy) * 224.0f;
    float rel1 = (gx - qcx) * 224.0f;
    float rc0 = cell[(size_t)qg * 2 + 0] * 224.0f;
    float rc1 = cell[(size_t)qg * 2 + 1] * 224.0f;
    const unsigned short* base = cfh + (size_t)b * cf_stride +
                                 (((size_t)iyc * kH2 + ixc) * 512);
    unsigned short ch_[8], cl_[8], sh_[8], sl_[8];
#pragma unroll
    for (int u = 0; u < 4; ++u) {
      const int k4 = ts * 16 + u * 4;
      ushort4 clo = *(const ushort4*)(base + k4);
      ushort4 chi = *(const ushort4*)(base + 128 + k4);
      ushort4 f0 = *(const ushort4*)(base + 256 + 2 * k4);
      ushort4 f1 = *(const ushort4*)(base + 256 + 2 * k4 + 4);
      float fr[8] = {h2f(f0.x), h2f(f0.y), h2f(f0.z), h2f(f0.w),
                     h2f(f1.x), h2f(f1.y), h2f(f1.z), h2f(f1.w)};
      float cl4[4] = {h2f(clo.x), h2f(clo.y), h2f(clo.z), h2f(clo.w)};
      float ch4[4] = {h2f(chi.x), h2f(chi.y), h2f(chi.z), h2f(chi.w)};
#pragma unroll
      for (int e = 0; e < 4; ++e) {
        const int k = k4 + e;
        float ph = rc0 * phw[2 * k] + rc1 * phw[2 * k + 1];
        float s = m * (fr[2 * e] * rel0 + fr[2 * e + 1] * rel1) + ph;
        float sv, cv;
        sincospif(s, &sv, &cv);
        float xc = m * cl4[e] * cv;
        float xsn = m * ch4[e] * sv;
        const int sl = (u & 1) * 4 + e;
        unsigned short h1_ = f2bf(xc);
        ch_[sl] = h1_; cl_[sl] = f2bf(xc - bf2f(h1_));
        unsigned short h2_ = f2bf(xsn);
        sh_[sl] = h2_; sl_[sl] = f2bf(xsn - bf2f(h2_));
      }
      if (u & 1) {
        const int kb = ts * 16 + (u - 1) * 4;
        uint4 v;
        v.x = (unsigned)ch_[0] | ((unsigned)ch_[1] << 16);
        v.y = (unsigned)ch_[2] | ((unsigned)ch_[3] << 16);
        v.z = (unsigned)ch_[4] | ((unsigned)ch_[5] << 16);
        v.w = (unsigned)ch_[6] | ((unsigned)ch_[7] << 16);
        *(uint4*)(Xs + tq * ROW + kb * 2) = v;
        v.x = (unsigned)cl_[0] | ((unsigned)cl_[1] << 16);
        v.y = (unsigned)cl_[2] | ((unsigned)cl_[3] << 16);
        v.z = (unsigned)cl_[4] | ((unsigned)cl_[5] << 16);
        v.w = (unsigned)cl_[6] | ((unsigned)cl_[7] << 16);
        *(uint4*)(Xs + PLANE + tq * ROW + kb * 2) = v;
        v.x = (unsigned)sh_[0] | ((unsigned)sh_[1] << 16);
        v.y = (unsigned)sh_[2] | ((unsigned)sh_[3] << 16);
        v.z = (unsigned)sh_[4] | ((unsigned)sh_[5] << 16);
        v.w = (unsigned)sh_[6] | ((unsigned)sh_[7] << 16);
        *(uint4*)(Xs + tq * ROW + (128 + kb) * 2) = v;
        v.x = (unsigned)sl_[0] | ((unsigned)sl_[1] << 16);
        v.y = (unsigned)sl_[2] | ((unsigned)sl_[3] << 16);
        v.z = (unsigned)sl_[4] | ((unsigned)sl_[5] << 16);
        v.w = (unsigned)sl_[6] | ((unsigned)sl_[7] << 16);
        *(uint4*)(Xs + PLANE + tq * ROW + (128 + kb) * 2) = v;
      }
    }
  }
  __syncthreads();

  const int w = t >> 6, lane = t & 63;
  const int quad = lane >> 4, ml = lane & 15;
  const unsigned int bvoff = (unsigned int)lane * 16u;

#pragma unroll
  for (int layer = 0; layer < 2; ++layer) {
    const unsigned short* wb = wmlp + layer * 131072;
    f4v acc[2][4];
#pragma unroll
    for (int i = 0; i < 2; ++i)
#pragma unroll
      for (int j = 0; j < 4; ++j) acc[i][j] = (f4v){0.0f, 0.0f, 0.0f, 0.0f};
#pragma unroll
    for (int kstep = 0; kstep < 8; ++kstep) {
      s8v Bh[4], Bl[4];
#pragma unroll
      for (int j = 0; j < 4; ++j) {
        unsigned int off = (unsigned int)((w * 4 + j) * 8 + kstep) * 1024u + bvoff;
        Bh[j] = *(const s8v*)((const char*)wb + off);
        Bl[j] = *(const s8v*)((const char*)(wb + 65536) + off);
      }
#pragma unroll
      for (int i = 0; i < 2; ++i) {
        const int aoff = (i * 16 + ml) * ROW + (kstep * 32 + quad * 8) * 2;
        s8v Ah = *(const s8v*)(Xs + aoff);
        s8v Al = *(const s8v*)(Xs + PLANE + aoff);
#pragma unroll
        for (int j = 0; j < 4; ++j) {
          acc[i][j] = __builtin_amdgcn_mfma_f32_16x16x32_bf16(Ah, Bh[j], acc[i][j], 0, 0, 0);
          acc[i][j] = __builtin_amdgcn_mfma_f32_16x16x32_bf16(Al, Bh[j], acc[i][j], 0, 0, 0);
          acc[i][j] = __builtin_amdgcn_mfma_f32_16x16x32_bf16(Ah, Bl[j], acc[i][j], 0, 0, 0);
        }
      }
    }
    __syncthreads();
    const float* bs = layer ? b2 : b1;
    float bj[4];
#pragma unroll
    for (int j = 0; j < 4; ++j) bj[j] = bs[w * 64 + j * 16 + ml];
    if (layer == 0) {
#pragma unroll
      for (int i = 0; i < 2; ++i)
#pragma unroll
        for (int j = 0; j < 4; ++j)
#pragma unroll
          for (int reg = 0; reg < 4; ++reg) {
            int m = i * 16 + quad * 4 + reg;
            int n = w * 64 + j * 16 + ml;
            float v = fmaxf(acc[i][j][reg] + bj[j], 0.0f);
            unsigned short hi = f2bf(v);
            unsigned short lo = f2bf(v - bf2f(hi));
            *(unsigned short*)(Xs + m * ROW + n * 2) = hi;
            *(unsigned short*)(Xs + PLANE + m * ROW + n * 2) = lo;
          }
    } else {
#pragma unroll
      for (int i = 0; i < 2; ++i)
#pragma unroll
        for (int j = 0; j < 4; ++j)
#pragma unroll
          for (int reg = 0; reg < 4; ++reg) {
            int m = i * 16 + quad * 4 + reg;
            int n = w * 64 + j * 16 + ml;
            float v = fmaxf(acc[i][j][reg] + bj[j], 0.0f);
            *(float*)(Xs + ((size_t)m * 264 + n) * 4) = v;
          }
    }
    __syncthreads();
  }

  // ---- phase 3: 3-wide output layer (8 threads per query) ----
  {
    const int tq = t >> 3, ts = t & 7;
    const float* xr = (const float*)(Xs + (size_t)tq * 264 * 4);
    float c0 = 0, c1 = 0, c2 = 0;
    for (int k = ts * 32; k < ts * 32 + 32; ++k) {
      float xv = xr[k];
      c0 += xv * w3[k];
      c1 += xv * w3[256 + k];
      c2 += xv * w3[512 + k];
    }
    c0 += __shfl_down(c0, 4, 8); c0 += __shfl_down(c0, 2, 8); c0 += __shfl_down(c0, 1, 8);
    c1 += __shfl_down(c1, 4, 8); c1 += __shfl_down(c1, 2, 8); c1 += __shfl_down(c1, 1, 8);
    c2 += __shfl_down(c2, 4, 8); c2 += __shfl_down(c2, 2, 8); c2 += __shfl_down(c2, 1, 8);
    if (ts == 0) {
      const int qg = q_base + blockIdx.x * 32 + tq;
      float* o = out + (size_t)qg * 3;
      o[0] = c0 + b3[0];
      o[1] = c1 + b3[1];
      o[2] = c2 + b3[2];
    }
  }
}

// ---------------- launch ----------------
extern "C" void kernel_launch(void* const* d_in, const int* in_sizes, int n_in,
                              void* d_out, int out_size, void* d_ws, size_t ws_size,
                              hipStream_t stream) {
  (void)in_sizes; (void)n_in; (void)out_size;
  const float* feat   = (const float*)d_in[0];
  const float* coord  = (const float*)d_in[1];
  const float* cell   = (const float*)d_in[2];
  const float* cls_w1 = (const float*)d_in[3];
  const float* cls_b1 = (const float*)d_in[4];
  const float* cls_w2 = (const float*)d_in[5];
  const float* cls_b2 = (const float*)d_in[6];
  const float* sigx   = (const float*)d_in[7];
  const float* sigy   = (const float*)d_in[8];
  const float* opac   = (const float*)d_in[9];
  const float* rho    = (const float*)d_in[10];
  const float* coef_w = (const float*)d_in[11];
  const float* coef_b = (const float*)d_in[12];
  const float* freq_w = (const float*)d_in[13];
  const float* freq_b = (const float*)d_in[14];
  const float* phw    = (const float*)d_in[15];
  const float* w1     = (const float*)d_in[16];
  const float* b1     = (const float*)d_in[17];
  const float* w2     = (const float*)d_in[18];
  const float* b2     = (const float*)d_in[19];
  const float* w3     = (const float*)d_in[20];
  const float* b3     = (const float*)d_in[21];

  const bool big = ws_size >= A_TOTAL;
  char* ws = (char*)d_ws;
  const size_t wbase = big ? A_WBASE : B_WBASE;
  unsigned short* fbh = (unsigned short*)(ws + (big ? A_FBH : B_FBH));
  unsigned short* fbl = (unsigned short*)(ws + (big ? A_FBL : B_FBL));
  unsigned short* gfh = (unsigned short*)(ws + (big ? A_GFH : B_GFH));
  unsigned short* gfl = (unsigned short*)(ws + (big ? A_GFL : B_GFL));
  float* h_buf = (float*)(ws + (big ? A_H : B_H));
  unsigned short* cfb = (unsigned short*)(ws + (big ? A_CF : B_CF));
  unsigned short* wph = (unsigned short*)(ws + wbase + W_WPH);
  unsigned short* wpl = (unsigned short*)(ws + wbase + W_WPL);
  unsigned short* w1h = (unsigned short*)(ws + wbase + W_W1H);
  unsigned short* w1l = (unsigned short*)(ws + wbase + W_W1L);
  unsigned short* wmlp = (unsigned short*)(ws + wbase + W_WMLP);
  float* wsums = (float*)(ws + wbase + W_WSUM);
  float* wk    = (float*)(ws + wbase + W_WK);
  float* outp  = (float*)d_out;

  hipLaunchKernelGGL(k_init, dim3(1), dim3(256), 0, stream, wsums);
  hipLaunchKernelGGL(k_prepw, dim3(1152), dim3(256), 0, stream, coef_w, freq_w, wph, wpl);
  hipLaunchKernelGGL(k_prepw1, dim3(144), dim3(256), 0, stream, cls_w1, w1h, w1l);
  hipLaunchKernelGGL(k_prepmlp, dim3(512), dim3(256), 0, stream, w1, w2, wmlp);
  hipLaunchKernelGGL(k_prepfeat, dim3(784), dim3(256), 0, stream, feat, fbh, fbl);
  hipLaunchKernelGGL(k_conv1_mfma, dim3(392), dim3(256), 0, stream,
                     fbh, fbl, w1h, w1l, cls_b1, h_buf);
  hipLaunchKernelGGL(k_wavg, dim3(196), dim3(256), 0, stream,
                     h_buf, cls_w2, cls_b2, sigx, sigy, opac, rho, wsums);
  hipLaunchKernelGGL(k_finalize, dim3(1), dim3(256), 0, stream, wsums, wk);

  if (big) {
    hipLaunchKernelGGL(k_splat, dim3(4 * 256), dim3(256), 0, stream, feat, wk, gfh, gfl);
    hipLaunchKernelGGL(k_conv2_mfma, dim3(4 * 784), dim3(256), 0, stream,
                       gfh, gfl, wph, wpl, coef_b, freq_b, cfb);
    hipLaunchKernelGGL(k_query_mfma, dim3(4 * 1568), dim3(256), 0, stream,
                       cfb, coord, cell, phw, wmlp, b1, b2, w3, b3, outp,
                       0, (size_t)kQ * 512);
  } else {
    for (int b = 0; b < kB; ++b) {
      const float* feat_b = feat + (size_t)b * 64 * kP1;
      hipLaunchKernelGGL(k_splat, dim3(256), dim3(256), 0, stream, feat_b, wk, gfh, gfl);
      hipLaunchKernelGGL(k_conv2_mfma, dim3(784), dim3(256), 0, stream,
                         gfh, gfl, wph, wpl, coef_b, freq_b, cfb);
      hipLaunchKernelGGL(k_query_mfma, dim3(1568), dim3(256), 0, stream,
                         cfb, coord, cell, phw, wmlp, b1, b2, w3, b3, outp,
                         b * kQ, (size_t)0);
    }
  }
}

// Round 16
// 710.001 us; speedup vs baseline: 1.2727x; 1.1234x over previous
//
#include <hip/hip_runtime.h>
#include <hip/hip_fp16.h>
#include <math.h>

// ---------------- problem constants ----------------
namespace {
constexpr int kB   = 4;
constexpr int kNG  = 100;
constexpr int kH1  = 112;            // feat H/W
constexpr int kH2  = 224;            // upscaled H/W
constexpr int kQ   = kH2 * kH2;      // 50176 queries per batch image
constexpr int kP1  = kH1 * kH1;      // 12544 pixels per image (feat res)

// ---- path B (per-image loop) workspace layout, ~79 MB ----
constexpr size_t B_FBH  = 0;
constexpr size_t B_FBL  = 6422528;
constexpr size_t B_GFH  = 0;
constexpr size_t B_GFL  = 6422528;
constexpr size_t B_H    = 12845056;
constexpr size_t B_CF   = 25690112;
constexpr size_t B_WBASE= B_CF + 51380224;

// ---- path A (batched) workspace layout, ~259 MB ----
constexpr size_t A_FBH  = 0;
constexpr size_t A_FBL  = 6422528;
constexpr size_t A_H    = 12845056;
constexpr size_t A_GFH  = 0;
constexpr size_t A_GFL  = 25690112;   // unused in fp16-gfeat mode (kept for layout stability)
constexpr size_t A_CF   = 51380224;
constexpr size_t A_WBASE= A_CF + 205520896;
constexpr size_t A_TOTAL= A_WBASE + 1893376;

// weight region offsets (relative to WBASE)
constexpr size_t W_WPH  = 0;
constexpr size_t W_WPL  = 589824;
constexpr size_t W_W1H  = 1179648;
constexpr size_t W_W1L  = 1253376;
constexpr size_t W_WMLP = 1327104;
constexpr size_t W_WSUM = 1851392;
constexpr size_t W_WK   = 1852416;
}  // namespace

using s8v = __attribute__((ext_vector_type(8))) short;     // 8 bf16 (4 VGPRs)
using h8v = __attribute__((ext_vector_type(8))) _Float16;  // 8 fp16 (4 VGPRs)
using f4v = __attribute__((ext_vector_type(4))) float;     // MFMA acc
using u4v = __attribute__((ext_vector_type(4))) unsigned int;

__device__ __forceinline__ unsigned short f2bf(float f) {
  unsigned int u = __float_as_uint(f);
  unsigned int r = u + 0x7fffu + ((u >> 16) & 1u);
  return (unsigned short)(r >> 16);
}
__device__ __forceinline__ float bf2f(unsigned short h) {
  return __uint_as_float((unsigned int)h << 16);
}
__device__ __forceinline__ unsigned short f2h(float f) {
  return __builtin_bit_cast(unsigned short, __float2half(f));
}
__device__ __forceinline__ float h2f(unsigned short u) {
  return __half2float(__builtin_bit_cast(__half, u));
}

// ---------------- tiny helpers ----------------
__global__ void k_init(float* wsums) {
  int t = threadIdx.x;
  if (t < 196) wsums[t] = 0.0f;
}

__global__ __launch_bounds__(256) void k_prepfeat(const float* __restrict__ feat,
                                                  unsigned short* __restrict__ fbh,
                                                  unsigned short* __restrict__ fbl) {
  __shared__ float ls[64 * 65];
  const int t = threadIdx.x;
  const int b = blockIdx.x / 196;
  const int seg = blockIdx.x % 196;
  const int pixbase = seg * 64;
  for (int idx = t; idx < 4096; idx += 256) {
    int ci = idx >> 6, px = idx & 63;
    ls[px * 65 + ci] = feat[((size_t)(b * 64 + ci)) * kP1 + pixbase + px];
  }
  __syncthreads();
  for (int idx = t; idx < 4096; idx += 256) {
    int px = idx >> 6, ci = idx & 63;
    float v = ls[px * 65 + ci];
    unsigned short hi = f2bf(v);
    unsigned short lo = f2bf(v - bf2f(hi));
    size_t o = ((size_t)(b * kP1 + pixbase + px)) * 64 + ci;
    fbh[o] = hi;
    fbl[o] = lo;
  }
}

// Pack conv2 weights into MFMA B-fragment order, split **fp16** hi/lo (round 16).
__global__ void k_prepw(const float* __restrict__ cw, const float* __restrict__ fw,
                        unsigned short* __restrict__ wph, unsigned short* __restrict__ wpl) {
  int e = blockIdx.x * 256 + threadIdx.x;   // 512*576
  int co = e / 576, k = e % 576;
  int ci = k & 63, kk = k >> 6;
  float v = (co < 256) ? cw[co * 576 + ci * 9 + kk] : fw[(co - 256) * 576 + ci * 9 + kk];
  unsigned short hi = f2h(v);
  unsigned short lo = f2h(v - h2f(hi));
  int n16 = co >> 4, nl = co & 15;
  int kstep = k >> 5, kr = k & 31;
  int dst = ((n16 * 18 + kstep) * 64 + (kr >> 3) * 16 + nl) * 8 + (kr & 7);
  wph[dst] = hi;
  wpl[dst] = lo;
}

__global__ void k_prepw1(const float* __restrict__ w1src,
                         unsigned short* __restrict__ wph, unsigned short* __restrict__ wpl) {
  int e = blockIdx.x * 256 + threadIdx.x;   // 64*576
  int co = e / 576, k = e % 576;
  int ci = k & 63, kk = k >> 6;
  float v = w1src[co * 576 + ci * 9 + kk];
  unsigned short hi = f2bf(v);
  unsigned short lo = f2bf(v - bf2f(hi));
  int n16 = co >> 4, nl = co & 15;
  int kstep = k >> 5, kr = k & 31;
  int dst = ((n16 * 18 + kstep) * 64 + (kr >> 3) * 16 + nl) * 8 + (kr & 7);
  wph[dst] = hi;
  wpl[dst] = lo;
}

__global__ void k_prepmlp(const float* __restrict__ w1, const float* __restrict__ w2,
                          unsigned short* __restrict__ wp) {
  int e = blockIdx.x * 256 + threadIdx.x;   // 131072
  int mat = e >> 16, idx = e & 65535;
  int j = idx >> 8, k = idx & 255;
  float v = (mat ? w2 : w1)[j * 256 + k];
  unsigned short hi = f2bf(v);
  unsigned short lo = f2bf(v - bf2f(hi));
  int n16 = j >> 4, nl = j & 15;
  int kstep = k >> 5, kr = k & 31;
  int dst = ((n16 * 8 + kstep) * 64 + (kr >> 3) * 16 + nl) * 8 + (kr & 7);
  wp[mat * 131072 + dst] = hi;
  wp[mat * 131072 + 65536 + dst] = lo;
}

// ---------------- conv1 as bf16x3 MFMA implicit GEMM ----------------
__global__ __launch_bounds__(256) void k_conv1_mfma(
    const unsigned short* __restrict__ fbh, const unsigned short* __restrict__ fbl,
    const unsigned short* __restrict__ wph, const unsigned short* __restrict__ wpl,
    const float* __restrict__ bias, float* __restrict__ outp) {
  __shared__ __attribute__((aligned(16))) char Asb[2 * 180 * 144];
  const int t = threadIdx.x;
  const int blk = blockIdx.x;          // 392
  const int b = blk / 98;
  const int mt = blk % 98;
  const int ty = mt / 14, tx = mt % 14;
  const int py0 = ty * 16, px0 = tx * 8;

  for (int idx = t; idx < 2880; idx += 256) {
    int plane = idx >= 1440;
    int r2 = plane ? idx - 1440 : idx;
    int p = r2 >> 3, c8 = r2 & 7;
    int pr = p / 10, pc = p % 10;
    int gy = py0 - 1 + pr, gx = px0 - 1 + pc;
    uint4 u = make_uint4(0u, 0u, 0u, 0u);
    if (gy >= 0 && gy < kH1 && gx >= 0 && gx < kH1) {
      const unsigned short* src = (plane ? fbl : fbh) +
          ((size_t)(b * kP1 + gy * kH1 + gx)) * 64 + c8 * 8;
      u = *(const uint4*)src;
    }
    *(uint4*)(Asb + plane * 25920 + p * 144 + c8 * 16) = u;
  }
  __syncthreads();

  const int w = t >> 6, lane = t & 63;
  const int quad = lane >> 4, ml = lane & 15;

  f4v acc[8];
#pragma unroll
  for (int i = 0; i < 8; ++i) acc[i] = (f4v){0.0f, 0.0f, 0.0f, 0.0f};

  const unsigned int bvoff = (unsigned int)lane * 16u;
#pragma unroll
  for (int kk = 0; kk < 9; ++kk) {
    const int ky = kk / 3, kx = kk % 3;
#pragma unroll
    for (int cs = 0; cs < 2; ++cs) {
      const int kstep = kk * 2 + cs;
      unsigned int off = ((unsigned int)(w * 18 + kstep)) * 1024u + bvoff;
      s8v Bh = *(const s8v*)((const char*)wph + off);
      s8v Bl = *(const s8v*)((const char*)wpl + off);
#pragma unroll
      for (int i = 0; i < 8; ++i) {
        const int aoff = ((2 * i + (ml >> 3) + ky) * 10 + (ml & 7) + kx) * 144 + cs * 64 + quad * 16;
        s8v Ah = *(const s8v*)(Asb + aoff);
        s8v Al = *(const s8v*)(Asb + 25920 + aoff);
        acc[i] = __builtin_amdgcn_mfma_f32_16x16x32_bf16(Ah, Bh, acc[i], 0, 0, 0);
        acc[i] = __builtin_amdgcn_mfma_f32_16x16x32_bf16(Al, Bh, acc[i], 0, 0, 0);
        acc[i] = __builtin_amdgcn_mfma_f32_16x16x32_bf16(Ah, Bl, acc[i], 0, 0, 0);
      }
    }
  }

  const float bv = bias[w * 16 + ml];
#pragma unroll
  for (int i = 0; i < 8; ++i)
#pragma unroll
    for (int reg = 0; reg < 4; ++reg) {
      int m = i * 16 + quad * 4 + reg;
      int Y = py0 + (m >> 3), X = px0 + (m & 7);
      outp[((size_t)(b * kP1 + Y * kH1 + X)) * 64 + w * 16 + ml] =
          fmaxf(acc[i][reg] + bv, 0.0f);
    }
}

// ---------------- 1x1 conv + softmax + weighted sums ----------------
__global__ __launch_bounds__(256) void k_wavg(
    const float* __restrict__ h, const float* __restrict__ w2, const float* __restrict__ b2,
    const float* __restrict__ sx, const float* __restrict__ sy,
    const float* __restrict__ op, const float* __restrict__ rho,
    float* __restrict__ wsums) {
  __shared__ float w2s[kNG * 64];
  __shared__ float prm[4 * kNG];
  __shared__ float b2s[kNG];
  __shared__ float pl[196];
  const int t = threadIdx.x;
  for (int i = t; i < kNG * 64; i += 256) w2s[i] = w2[i];
  if (t < kNG) {
    prm[t] = sx[t];
    prm[kNG + t] = sy[t];
    prm[2 * kNG + t] = op[t];
    prm[3 * kNG + t] = rho[t];
    b2s[t] = b2[t];
  }
  if (t < 196) pl[t] = 0.0f;
  __syncthreads();
  const int id = blockIdx.x * 256 + t;
  float hreg[64];
  const float4* hp = (const float4*)(h + (size_t)id * 64);
#pragma unroll
  for (int i = 0; i < 16; ++i) {
    float4 v = hp[i];
    hreg[4 * i] = v.x; hreg[4 * i + 1] = v.y;
    hreg[4 * i + 2] = v.z; hreg[4 * i + 3] = v.w;
  }
  float S = 0, Sx = 0, Sy = 0, So = 0, Sr = 0;
  for (int g = 0; g < kNG; ++g) {
    float d = b2s[g];
    const float4* wp = (const float4*)(w2s + g * 64);
#pragma unroll
    for (int i = 0; i < 16; ++i) {
      float4 w = wp[i];
      d += hreg[4 * i] * w.x + hreg[4 * i + 1] * w.y +
           hreg[4 * i + 2] * w.z + hreg[4 * i + 3] * w.w;
    }
    float e = expf(d);
    S += e;
    Sx += e * prm[g];
    Sy += e * prm[kNG + g];
    So += e * prm[2 * kNG + g];
    Sr += e * prm[3 * kNG + g];
  }
  const int rem = id % (kH1 * kH1);
  const int p = ((rem / kH1) % 7) * 7 + ((rem % kH1) % 7);
  const float inv = 1.0f / S;
  atomicAdd(&pl[p], Sx * inv);
  atomicAdd(&pl[49 + p], Sy * inv);
  atomicAdd(&pl[98 + p], So * inv);
  atomicAdd(&pl[147 + p], Sr * inv);
  __syncthreads();
  if (t < 196) atomicAdd(&wsums[t], pl[t]);
}

// ---------------- build wk[p][h][w] ----------------
__global__ __launch_bounds__(256) void k_finalize(const float* __restrict__ wsums,
                                                  float* __restrict__ wk) {
  __shared__ float kern_s[49 * 25];
  __shared__ float wavg_s[196];
  const int t = threadIdx.x;
  if (t < 196) wavg_s[t] = wsums[t] * (1.0f / 1024.0f);
  __syncthreads();
  if (t < 49) {
    float wsx = wavg_s[t], wsy = wavg_s[49 + t], wr = wavg_s[147 + t];
    float c00 = wsx * wsx + 1e-5f;
    float c11 = wsy * wsy + 1e-5f;
    float c01 = wr * wsx * wsy;
    float det = c00 * c11 - c01 * c01;
    float i00 = c11 / det, i11 = c00 / det, i01 = -c01 / det;
    float nrm = 1.0f / (2.0f * 3.14159265358979323846f * sqrtf(det));
    float vals[25];
    float mx = -1e30f;
#pragma unroll
    for (int i = 0; i < 5; ++i) {
#pragma unroll
      for (int j = 0; j < 5; ++j) {
        float yv = -5.0f + 2.5f * (float)i;
        float xv = -5.0f + 2.5f * (float)j;
        float z = -0.5f * (i00 * xv * xv + 2.0f * i01 * xv * yv + i11 * yv * yv);
        float v = expf(z) * nrm;
        vals[i * 5 + j] = v;
        mx = fmaxf(mx, v);
      }
    }
#pragma unroll
    for (int k = 0; k < 25; ++k) kern_s[t * 25 + k] = vals[k] / mx;
  }
  __syncthreads();
  for (int idx = t; idx < 49 * 196; idx += 256) {
    const int p = idx / 196;
    const int hw = idx % 196;
    const int hh = hw / 14, ww = hw % 14;
    float txv = (0.5f - (float)(p / 7) / 7.0f) * 2.0f;
    float tyv = (0.5f - (float)(p % 7) / 7.0f) * 2.0f;
    float gxv = (-1.0f + (float)ww * (2.0f / 13.0f)) + txv;
    float gyv = (-1.0f + (float)hh * (2.0f / 13.0f)) + tyv;
    float pxv = (gxv + 1.0f) * 0.5f * 13.0f;
    float pyv = (gyv + 1.0f) * 0.5f * 13.0f;
    float x0f = floorf(pxv), y0f = floorf(pyv);
    int x0 = (int)x0f, y0 = (int)y0f;
    float wx = pxv - x0f, wy = pyv - y0f;
    auto samp = [&](int yi, int xi) -> float {
      if (yi < 4 || yi >= 9 || xi < 4 || xi >= 9) return 0.0f;
      return kern_s[p * 25 + (yi - 4) * 5 + (xi - 4)];
    };
    float kt = samp(y0, x0) * (1.0f - wy) * (1.0f - wx) +
               samp(y0, x0 + 1) * (1.0f - wy) * wx +
               samp(y0 + 1, x0) * wy * (1.0f - wx) +
               samp(y0 + 1, x0 + 1) * wy * wx;
    wk[idx] = wavg_s[98 + p] * kt;
  }
}

// ---------------- splat (batch-decoded) -> single fp16 gfeat plane (round 16) ----------------
__global__ __launch_bounds__(256) void k_splat(const float* __restrict__ feat,
                                               const float* __restrict__ wk,
                                               unsigned short* __restrict__ gfh) {
  __shared__ float fs[64 * 49];
  __shared__ float wks[49 * 196];
  const int t = threadIdx.x;
  const int b = blockIdx.x >> 8;
  const int rem = blockIdx.x & 255;
  const int ry = rem >> 4, rx = rem & 15;
  const float* featb = feat + (size_t)b * 64 * kP1;
  for (int idx = t; idx < 64 * 49; idx += 256) {
    int ci = idx / 49, p = idx % 49;
    int gy = ry * 7 + p / 7, gx = rx * 7 + p % 7;
    fs[idx] = featb[((size_t)ci * kH1 + gy) * kH1 + gx];
  }
  for (int idx = t; idx < 49 * 196; idx += 256) wks[idx] = wk[idx];
  __syncthreads();
  const int ci = t & 63;
  const int s = t >> 6;
  const int h0 = (s >> 1) * 7, w0 = (s & 1) * 7;
  float acc[49];
#pragma unroll
  for (int i = 0; i < 49; ++i) acc[i] = 0.0f;
  for (int p = 0; p < 49; ++p) {
    float f = fs[ci * 49 + p];
#pragma unroll
    for (int i = 0; i < 7; ++i)
#pragma unroll
      for (int j = 0; j < 7; ++j)
        acc[i * 7 + j] += f * wks[p * 196 + (h0 + i) * 14 + (w0 + j)];
  }
#pragma unroll
  for (int i = 0; i < 7; ++i)
#pragma unroll
    for (int j = 0; j < 7; ++j) {
      int Y = ry * 14 + h0 + i;
      int X = rx * 14 + w0 + j;
      float v = fminf(fmaxf(acc[i * 7 + j], 0.0f), 1.0f);
      gfh[((size_t)(b * kQ + Y * kH2 + X)) * 64 + ci] = f2h(v);
    }
}

// ---------------- conv2: fp16x2 MFMA implicit GEMM, wave tile M=64 x N=128 ----------------
// Round 16: gfeat in [0,1] fits fp16 at the same 2^-11 relative error as cf's
// fp16 storage (r6) — the bf16x3 split's 2^-17 was wasted precision. A=fp16
// single plane, B=fp16 hi/lo -> 2 MFMA/step (floor 171->114 us), A-LDS reads
// and halo fetch halve, LDS 51.8->25.9 KB.
__global__ __launch_bounds__(256) void k_conv2_mfma(
    const unsigned short* __restrict__ gfh,
    const unsigned short* __restrict__ wph, const unsigned short* __restrict__ wpl,
    const float* __restrict__ coef_b, const float* __restrict__ freq_b,
    unsigned short* __restrict__ outp) {     // fp16 [NB*224*224][512]
  __shared__ __attribute__((aligned(16))) char Asb[180 * 144];  // 25,920 B
  const int t = threadIdx.x;
  const int b = blockIdx.x / 784;
  const int blk = blockIdx.x % 784;
  const int nb = blk & 1;
  const int mt = blk >> 1;
  const int ty = mt / 28, tx = mt % 28;
  const int py0 = ty * 16, px0 = tx * 8;

  for (int idx = t; idx < 1440; idx += 256) {
    int p = idx >> 3, c8 = idx & 7;
    int pr = p / 10, pc = p % 10;
    int gy = py0 - 1 + pr, gx = px0 - 1 + pc;
    uint4 u = make_uint4(0u, 0u, 0u, 0u);
    if (gy >= 0 && gy < kH2 && gx >= 0 && gx < kH2) {
      const unsigned short* src = gfh + ((size_t)(b * kQ + gy * kH2 + gx)) * 64 + c8 * 8;
      u = *(const uint4*)src;
    }
    *(uint4*)(Asb + p * 144 + c8 * 16) = u;
  }
  __syncthreads();

  const int w = t >> 6, lane = t & 63;
  const int quad = lane >> 4, ml = lane & 15;
  const int mh = w & 1;            // M-half (pixels mh*64 .. +64)
  const int nh = w >> 1;           // N-half within this nb (128 co)
  const unsigned int bvoff = (unsigned int)lane * 16u;

  f4v acc[4][8];
#pragma unroll
  for (int i = 0; i < 4; ++i)
#pragma unroll
    for (int j = 0; j < 8; ++j) acc[i][j] = (f4v){0.0f, 0.0f, 0.0f, 0.0f};

#pragma unroll
  for (int kk = 0; kk < 9; ++kk) {
    const int ky = kk / 3, kx = kk % 3;
#pragma unroll
    for (int cs = 0; cs < 2; ++cs) {
      const int kstep = kk * 2 + cs;
      h8v Bh[8], Bl[8];
#pragma unroll
      for (int j = 0; j < 8; ++j) {
        unsigned int off = ((unsigned int)((nb * 16 + nh * 8 + j) * 18 + kstep)) * 1024u + bvoff;
        Bh[j] = *(const h8v*)((const char*)wph + off);
        Bl[j] = *(const h8v*)((const char*)wpl + off);
      }
#pragma unroll
      for (int i = 0; i < 4; ++i) {
        const int aoff = ((mh * 8 + 2 * i + (ml >> 3) + ky) * 10 + (ml & 7) + kx) * 144 +
                         cs * 64 + quad * 16;
        h8v Ah = *(const h8v*)(Asb + aoff);
#pragma unroll
        for (int j = 0; j < 8; ++j) {
          acc[i][j] = __builtin_amdgcn_mfma_f32_16x16x32_f16(Ah, Bh[j], acc[i][j], 0, 0, 0);
          acc[i][j] = __builtin_amdgcn_mfma_f32_16x16x32_f16(Ah, Bl[j], acc[i][j], 0, 0, 0);
        }
      }
    }
  }

  // ---- epilogue via LDS (16-pixel chunks), fp16 nt stores ----
  float bj[8];
#pragma unroll
  for (int j = 0; j < 8; ++j) {
    int co = nb * 256 + nh * 128 + j * 16 + ml;
    bj[j] = (co < 256) ? coef_b[co] : freq_b[co - 256];
  }
  __syncthreads();               // A-tile dead; reuse as staging
  float* Ls = (float*)Asb;       // [16 pixels][268 floats] = 17,152 B (fits 25.9 KB)
  const int pq = t >> 4;
  const int ts2 = t & 15;
#pragma unroll
  for (int c = 0; c < 8; ++c) {
    if ((c >> 2) == mh) {
      const int i = c & 3;
#pragma unroll
      for (int j = 0; j < 8; ++j)
#pragma unroll
        for (int reg = 0; reg < 4; ++reg)
          Ls[(quad * 4 + reg) * 268 + nh * 128 + j * 16 + ml] = acc[i][j][reg] + bj[j];
    }
    __syncthreads();
    const int m = c * 16 + pq;
    const int Y = py0 + (m >> 3), X = px0 + (m & 7);
    unsigned short* orow = outp + ((size_t)(b * kQ + Y * kH2 + X)) * 512 + nb * 256;
    const float* lrow = Ls + pq * 268;
#pragma unroll
    for (int u = 0; u < 2; ++u) {
      float4 a = *(const float4*)(lrow + ts2 * 16 + u * 8);
      float4 bb = *(const float4*)(lrow + ts2 * 16 + u * 8 + 4);
      u4v v;
      v.x = (unsigned)f2h(a.x) | ((unsigned)f2h(a.y) << 16);
      v.y = (unsigned)f2h(a.z) | ((unsigned)f2h(a.w) << 16);
      v.z = (unsigned)f2h(bb.x) | ((unsigned)f2h(bb.y) << 16);
      v.w = (unsigned)f2h(bb.z) | ((unsigned)f2h(bb.w) << 16);
      __builtin_nontemporal_store(v, (u4v*)(orow + ts2 * 16 + u * 8));
    }
    __syncthreads();
  }
}

// ---------------- fused query: r12/r13 config (M=32/wave, N=64/wave) ----------------
__global__ __launch_bounds__(256) void k_query_mfma(
    const unsigned short* __restrict__ cfh,
    const float* __restrict__ coord,
    const float* __restrict__ cell, const float* __restrict__ phw,
    const unsigned short* __restrict__ wmlp,   // [2][hi/lo][65536]
    const float* __restrict__ b1, const float* __restrict__ b2,
    const float* __restrict__ w3, const float* __restrict__ b3,
    float* __restrict__ out, int q_base, size_t cf_stride) {
  __shared__ __attribute__((aligned(16))) char Xs[2 * 32 * 264 * 2];  // 33,792 B
  constexpr int ROW = 264 * 2;
  constexpr int PLANE = 32 * 264 * 2;
  const int t = threadIdx.x;

  // ---- phase 1: gather + basis (8 threads per query, 32 queries) ----
  {
    const int tq = t >> 3, ts = t & 7;
    const int qg = q_base + blockIdx.x * 32 + tq;
    const int b = qg / kQ;
    float gy = coord[(size_t)qg * 2 + 0];
    float gx = coord[(size_t)qg * 2 + 1];
    float fx = ((gx + 1.0f) * 224.0f - 1.0f) * 0.5f;
    float fy = ((gy + 1.0f) * 224.0f - 1.0f) * 0.5f;
    int ix = (int)rintf(fx);
    int iy = (int)rintf(fy);
    bool ok = (ix >= 0) && (ix < 224) && (iy >= 0) && (iy < 224);
    int ixc = min(max(ix, 0), 223);
    int iyc = min(max(iy, 0), 223);
    float m = ok ? 1.0f : 0.0f;
    float qcy = ok ? (-1.0f + (1.0f / 224.0f) + (2.0f / 224.0f) * (float)iyc) : 0.0f;
    float qcx = ok ? (-1.0f + (1.0f / 224.0f) + (2.0f / 224.0f) * (float)ixc) : 0.0f;
    float rel0 = (gy - qcy) * 224.0f;
    float rel1 = (gx - qcx) * 224.0f;
    float rc0 = cell[(size_t)qg * 2 + 0] * 224.0f;
    float rc1 = cell[(size_t)qg * 2 + 1] * 224.0f;
    const unsigned short* base = cfh + (size_t)b * cf_stride +
                                 (((size_t)iyc * kH2 + ixc) * 512);
    unsigned short ch_[8], cl_[8], sh_[8], sl_[8];
#pragma unroll
    for (int u = 0; u < 4; ++u) {
      const int k4 = ts * 16 + u * 4;
      ushort4 clo = *(const ushort4*)(base + k4);
      ushort4 chi = *(const ushort4*)(base + 128 + k4);
      ushort4 f0 = *(const ushort4*)(base + 256 + 2 * k4);
      ushort4 f1 = *(const ushort4*)(base + 256 + 2 * k4 + 4);
      float fr[8] = {h2f(f0.x), h2f(f0.y), h2f(f0.z), h2f(f0.w),
                     h2f(f1.x), h2f(f1.y), h2f(f1.z), h2f(f1.w)};
      float cl4[4] = {h2f(clo.x), h2f(clo.y), h2f(clo.z), h2f(clo.w)};
      float ch4[4] = {h2f(chi.x), h2f(chi.y), h2f(chi.z), h2f(chi.w)};
#pragma unroll
      for (int e = 0; e < 4; ++e) {
        const int k = k4 + e;
        float ph = rc0 * phw[2 * k] + rc1 * phw[2 * k + 1];
        float s = m * (fr[2 * e] * rel0 + fr[2 * e + 1] * rel1) + ph;
        float sv, cv;
        sincospif(s, &sv, &cv);
        float xc = m * cl4[e] * cv;
        float xsn = m * ch4[e] * sv;
        const int sl = (u & 1) * 4 + e;
        unsigned short h1_ = f2bf(xc);
        ch_[sl] = h1_; cl_[sl] = f2bf(xc - bf2f(h1_));
        unsigned short h2_ = f2bf(xsn);
        sh_[sl] = h2_; sl_[sl] = f2bf(xsn - bf2f(h2_));
      }
      if (u & 1) {
        const int kb = ts * 16 + (u - 1) * 4;
        uint4 v;
        v.x = (unsigned)ch_[0] | ((unsigned)ch_[1] << 16);
        v.y = (unsigned)ch_[2] | ((unsigned)ch_[3] << 16);
        v.z = (unsigned)ch_[4] | ((unsigned)ch_[5] << 16);
        v.w = (unsigned)ch_[6] | ((unsigned)ch_[7] << 16);
        *(uint4*)(Xs + tq * ROW + kb * 2) = v;
        v.x = (unsigned)cl_[0] | ((unsigned)cl_[1] << 16);
        v.y = (unsigned)cl_[2] | ((unsigned)cl_[3] << 16);
        v.z = (unsigned)cl_[4] | ((unsigned)cl_[5] << 16);
        v.w = (unsigned)cl_[6] | ((unsigned)cl_[7] << 16);
        *(uint4*)(Xs + PLANE + tq * ROW + kb * 2) = v;
        v.x = (unsigned)sh_[0] | ((unsigned)sh_[1] << 16);
        v.y = (unsigned)sh_[2] | ((unsigned)sh_[3] << 16);
        v.z = (unsigned)sh_[4] | ((unsigned)sh_[5] << 16);
        v.w = (unsigned)sh_[6] | ((unsigned)sh_[7] << 16);
        *(uint4*)(Xs + tq * ROW + (128 + kb) * 2) = v;
        v.x = (unsigned)sl_[0] | ((unsigned)sl_[1] << 16);
        v.y = (unsigned)sl_[2] | ((unsigned)sl_[3] << 16);
        v.z = (unsigned)sl_[4] | ((unsigned)sl_[5] << 16);
        v.w = (unsigned)sl_[6] | ((unsigned)sl_[7] << 16);
        *(uint4*)(Xs + PLANE + tq * ROW + (128 + kb) * 2) = v;
      }
    }
  }
  __syncthreads();

  const int w = t >> 6, lane = t & 63;
  const int quad = lane >> 4, ml = lane & 15;
  const unsigned int bvoff = (unsigned int)lane * 16u;

#pragma unroll
  for (int layer = 0; layer < 2; ++layer) {
    const unsigned short* wb = wmlp + layer * 131072;
    f4v acc[2][4];
#pragma unroll
    for (int i = 0; i < 2; ++i)
#pragma unroll
      for (int j = 0; j < 4; ++j) acc[i][j] = (f4v){0.0f, 0.0f, 0.0f, 0.0f};
#pragma unroll
    for (int kstep = 0; kstep < 8; ++kstep) {
      s8v Bh[4], Bl[4];
#pragma unroll
      for (int j = 0; j < 4; ++j) {
        unsigned int off = (unsigned int)((w * 4 + j) * 8 + kstep) * 1024u + bvoff;
        Bh[j] = *(const s8v*)((const char*)wb + off);
        Bl[j] = *(const s8v*)((const char*)(wb + 65536) + off);
      }
#pragma unroll
      for (int i = 0; i < 2; ++i) {
        const int aoff = (i * 16 + ml) * ROW + (kstep * 32 + quad * 8) * 2;
        s8v Ah = *(const s8v*)(Xs + aoff);
        s8v Al = *(const s8v*)(Xs + PLANE + aoff);
#pragma unroll
        for (int j = 0; j < 4; ++j) {
          acc[i][j] = __builtin_amdgcn_mfma_f32_16x16x32_bf16(Ah, Bh[j], acc[i][j], 0, 0, 0);
          acc[i][j] = __builtin_amdgcn_mfma_f32_16x16x32_bf16(Al, Bh[j], acc[i][j], 0, 0, 0);
          acc[i][j] = __builtin_amdgcn_mfma_f32_16x16x32_bf16(Ah, Bl[j], acc[i][j], 0, 0, 0);
        }
      }
    }
    __syncthreads();
    const float* bs = layer ? b2 : b1;
    float bj[4];
#pragma unroll
    for (int j = 0; j < 4; ++j) bj[j] = bs[w * 64 + j * 16 + ml];
    if (layer == 0) {
#pragma unroll
      for (int i = 0; i < 2; ++i)
#pragma unroll
        for (int j = 0; j < 4; ++j)
#pragma unroll
          for (int reg = 0; reg < 4; ++reg) {
            int m = i * 16 + quad * 4 + reg;
            int n = w * 64 + j * 16 + ml;
            float v = fmaxf(acc[i][j][reg] + bj[j], 0.0f);
            unsigned short hi = f2bf(v);
            unsigned short lo = f2bf(v - bf2f(hi));
            *(unsigned short*)(Xs + m * ROW + n * 2) = hi;
            *(unsigned short*)(Xs + PLANE + m * ROW + n * 2) = lo;
          }
    } else {
#pragma unroll
      for (int i = 0; i < 2; ++i)
#pragma unroll
        for (int j = 0; j < 4; ++j)
#pragma unroll
          for (int reg = 0; reg < 4; ++reg) {
            int m = i * 16 + quad * 4 + reg;
            int n = w * 64 + j * 16 + ml;
            float v = fmaxf(acc[i][j][reg] + bj[j], 0.0f);
            *(float*)(Xs + ((size_t)m * 264 + n) * 4) = v;
          }
    }
    __syncthreads();
  }

  // ---- phase 3: 3-wide output layer (8 threads per query) ----
  {
    const int tq = t >> 3, ts = t & 7;
    const float* xr = (const float*)(Xs + (size_t)tq * 264 * 4);
    float c0 = 0, c1 = 0, c2 = 0;
    for (int k = ts * 32; k < ts * 32 + 32; ++k) {
      float xv = xr[k];
      c0 += xv * w3[k];
      c1 += xv * w3[256 + k];
      c2 += xv * w3[512 + k];
    }
    c0 += __shfl_down(c0, 4, 8); c0 += __shfl_down(c0, 2, 8); c0 += __shfl_down(c0, 1, 8);
    c1 += __shfl_down(c1, 4, 8); c1 += __shfl_down(c1, 2, 8); c1 += __shfl_down(c1, 1, 8);
    c2 += __shfl_down(c2, 4, 8); c2 += __shfl_down(c2, 2, 8); c2 += __shfl_down(c2, 1, 8);
    if (ts == 0) {
      const int qg = q_base + blockIdx.x * 32 + tq;
      float* o = out + (size_t)qg * 3;
      o[0] = c0 + b3[0];
      o[1] = c1 + b3[1];
      o[2] = c2 + b3[2];
    }
  }
}

// ---------------- launch ----------------
extern "C" void kernel_launch(void* const* d_in, const int* in_sizes, int n_in,
                              void* d_out, int out_size, void* d_ws, size_t ws_size,
                              hipStream_t stream) {
  (void)in_sizes; (void)n_in; (void)out_size;
  const float* feat   = (const float*)d_in[0];
  const float* coord  = (const float*)d_in[1];
  const float* cell   = (const float*)d_in[2];
  const float* cls_w1 = (const float*)d_in[3];
  const float* cls_b1 = (const float*)d_in[4];
  const float* cls_w2 = (const float*)d_in[5];
  const float* cls_b2 = (const float*)d_in[6];
  const float* sigx   = (const float*)d_in[7];
  const float* sigy   = (const float*)d_in[8];
  const float* opac   = (const float*)d_in[9];
  const float* rho    = (const float*)d_in[10];
  const float* coef_w = (const float*)d_in[11];
  const float* coef_b = (const float*)d_in[12];
  const float* freq_w = (const float*)d_in[13];
  const float* freq_b = (const float*)d_in[14];
  const float* phw    = (const float*)d_in[15];
  const float* w1     = (const float*)d_in[16];
  const float* b1     = (const float*)d_in[17];
  const float* w2     = (const float*)d_in[18];
  const float* b2     = (const float*)d_in[19];
  const float* w3     = (const float*)d_in[20];
  const float* b3     = (const float*)d_in[21];

  const bool big = ws_size >= A_TOTAL;
  char* ws = (char*)d_ws;
  const size_t wbase = big ? A_WBASE : B_WBASE;
  unsigned short* fbh = (unsigned short*)(ws + (big ? A_FBH : B_FBH));
  unsigned short* fbl = (unsigned short*)(ws + (big ? A_FBL : B_FBL));
  unsigned short* gfh = (unsigned short*)(ws + (big ? A_GFH : B_GFH));
  float* h_buf = (float*)(ws + (big ? A_H : B_H));
  unsigned short* cfb = (unsigned short*)(ws + (big ? A_CF : B_CF));
  unsigned short* wph = (unsigned short*)(ws + wbase + W_WPH);
  unsigned short* wpl = (unsigned short*)(ws + wbase + W_WPL);
  unsigned short* w1h = (unsigned short*)(ws + wbase + W_W1H);
  unsigned short* w1l = (unsigned short*)(ws + wbase + W_W1L);
  unsigned short* wmlp = (unsigned short*)(ws + wbase + W_WMLP);
  float* wsums = (float*)(ws + wbase + W_WSUM);
  float* wk    = (float*)(ws + wbase + W_WK);
  float* outp  = (float*)d_out;

  hipLaunchKernelGGL(k_init, dim3(1), dim3(256), 0, stream, wsums);
  hipLaunchKernelGGL(k_prepw, dim3(1152), dim3(256), 0, stream, coef_w, freq_w, wph, wpl);
  hipLaunchKernelGGL(k_prepw1, dim3(144), dim3(256), 0, stream, cls_w1, w1h, w1l);
  hipLaunchKernelGGL(k_prepmlp, dim3(512), dim3(256), 0, stream, w1, w2, wmlp);
  hipLaunchKernelGGL(k_prepfeat, dim3(784), dim3(256), 0, stream, feat, fbh, fbl);
  hipLaunchKernelGGL(k_conv1_mfma, dim3(392), dim3(256), 0, stream,
                     fbh, fbl, w1h, w1l, cls_b1, h_buf);
  hipLaunchKernelGGL(k_wavg, dim3(196), dim3(256), 0, stream,
                     h_buf, cls_w2, cls_b2, sigx, sigy, opac, rho, wsums);
  hipLaunchKernelGGL(k_finalize, dim3(1), dim3(256), 0, stream, wsums, wk);

  if (big) {
    hipLaunchKernelGGL(k_splat, dim3(4 * 256), dim3(256), 0, stream, feat, wk, gfh);
    hipLaunchKernelGGL(k_conv2_mfma, dim3(4 * 784), dim3(256), 0, stream,
                       gfh, wph, wpl, coef_b, freq_b, cfb);
    hipLaunchKernelGGL(k_query_mfma, dim3(4 * 1568), dim3(256), 0, stream,
                       cfb, coord, cell, phw, wmlp, b1, b2, w3, b3, outp,
                       0, (size_t)kQ * 512);
  } else {
    for (int b = 0; b < kB; ++b) {
      const float* feat_b = feat + (size_t)b * 64 * kP1;
      // per-image path: k_splat decodes b from blockIdx (grid 256 -> b=0)
      hipLaunchKernelGGL(k_splat, dim3(256), dim3(256), 0, stream, feat_b, wk, gfh);
      hipLaunchKernelGGL(k_conv2_mfma, dim3(784), dim3(256), 0, stream,
                         gfh, wph, wpl, coef_b, freq_b, cfb);
      hipLaunchKernelGGL(k_query_mfma, dim3(1568), dim3(256), 0, stream,
                         cfb, coord, cell, phw, wmlp, b1, b2, w3, b3, outp,
                         b * kQ, (size_t)0);
    }
  }
}